// Round 2
// baseline (2283.522 us; speedup 1.0000x reference)
//
#include <hip/hip_runtime.h>

#define B_ 2
#define S_ 2048
#define E_ 1024
#define H_ 16
#define HD_ 64

// ---------------------------------------------------------------------------
// GEMM: C = A @ W^T + bias
//   A: [M,K] row-major, W: [N,K] row-major (torch Linear convention), bias[N]
//   mode 0: C[m*N + n]                  (plain row-major, final projection)
//   mode 1: C[((b*H + h)*S + s)*HD + d] (scatter to [B,H,S,HD] for Q/K/V)
// 64x64 tile, K-step 32, 256 threads, 4x4 micro-tile per thread.
// ---------------------------------------------------------------------------
__global__ __launch_bounds__(256)
void gemm_xwt(const float* __restrict__ A, const float* __restrict__ W,
              const float* __restrict__ bias, float* __restrict__ C,
              int M, int N, int K, int mode)
{
    __shared__ float As[64][33];
    __shared__ float Ws[64][33];
    const int t  = threadIdx.x;
    const int m0 = blockIdx.y * 64;
    const int n0 = blockIdx.x * 64;
    const int tr = t >> 4;    // 0..15
    const int tc = t & 15;    // 0..15

    float acc[4][4] = {};

    for (int k0 = 0; k0 < K; k0 += 32) {
        // stage 64x32 tiles of A and W; 512 float4 each, 2 per thread
        #pragma unroll
        for (int i = 0; i < 2; ++i) {
            int idx = t + i * 256;          // float4 index
            int row = idx >> 3;             // 8 float4 per row
            int col = (idx & 7) * 4;
            float4 av = *(const float4*)&A[(size_t)(m0 + row) * K + k0 + col];
            As[row][col+0] = av.x; As[row][col+1] = av.y;
            As[row][col+2] = av.z; As[row][col+3] = av.w;
            float4 wv = *(const float4*)&W[(size_t)(n0 + row) * K + k0 + col];
            Ws[row][col+0] = wv.x; Ws[row][col+1] = wv.y;
            Ws[row][col+2] = wv.z; Ws[row][col+3] = wv.w;
        }
        __syncthreads();

        #pragma unroll
        for (int kk = 0; kk < 32; ++kk) {
            float a[4], w[4];
            #pragma unroll
            for (int i = 0; i < 4; ++i) a[i] = As[tr + i*16][kk];
            #pragma unroll
            for (int j = 0; j < 4; ++j) w[j] = Ws[tc + j*16][kk];
            #pragma unroll
            for (int i = 0; i < 4; ++i)
                #pragma unroll
                for (int j = 0; j < 4; ++j)
                    acc[i][j] += a[i] * w[j];
        }
        __syncthreads();
    }

    #pragma unroll
    for (int i = 0; i < 4; ++i) {
        int m = m0 + tr + i*16;
        #pragma unroll
        for (int j = 0; j < 4; ++j) {
            int n = n0 + tc + j*16;
            float v = acc[i][j] + bias[n];
            if (mode == 0) {
                C[(size_t)m * N + n] = v;
            } else {
                int b = m >> 11, s = m & (S_ - 1);   // m = b*S + s
                int h = n >> 6,  d = n & (HD_ - 1);  // n = h*HD + d
                C[(((size_t)(b * H_ + h)) * S_ + s) * HD_ + d] = v;
            }
        }
    }
}

// ---------------------------------------------------------------------------
// Flash-style attention, fp32.
//   Q,K,V: [B,H,S,HD].  O: [B,S,E] (so the output projection reads row-major).
//   Block: 256 threads = one (b,h) x 64 q-rows.  K/V tiles of 64 rows in LDS.
//   Thread t owns q-row r = t>>2, 16 output dims c = (t&3)*16 .. +15.
//   Row softmax state (m,l) replicated across the 4 quad threads via shfl_xor.
// ---------------------------------------------------------------------------
__global__ __launch_bounds__(256)
void attn_fwd(const float* __restrict__ Q, const float* __restrict__ K,
              const float* __restrict__ V, float* __restrict__ O)
{
    __shared__ float Qs[64][65];
    __shared__ float Ks[64][65];
    __shared__ float Vs[64][65];
    __shared__ float Ps[64][65];

    const int t  = threadIdx.x;
    const int bh = blockIdx.y;              // b*H + h
    const int q0 = blockIdx.x * 64;
    const size_t base = (size_t)bh * S_ * HD_;
    const int r  = t >> 2;                  // q-row in tile
    const int cq = t & 3;                   // 16-col group

    // load Q tile, folding in 1/sqrt(HD)
    const float sc = 0.125f;
    #pragma unroll
    for (int i = 0; i < 4; ++i) {
        int idx = t + i * 256;              // float4 index, 16 per row
        int row = idx >> 4;
        int col = (idx & 15) * 4;
        float4 qv = *(const float4*)&Q[base + (size_t)(q0 + row) * HD_ + col];
        Qs[row][col+0] = qv.x * sc; Qs[row][col+1] = qv.y * sc;
        Qs[row][col+2] = qv.z * sc; Qs[row][col+3] = qv.w * sc;
    }

    float mrun = -1e30f, lrun = 0.f;
    float o[16];
    #pragma unroll
    for (int j = 0; j < 16; ++j) o[j] = 0.f;

    for (int kt = 0; kt < S_ / 64; ++kt) {
        __syncthreads();   // prev iter's reads of Ks/Vs done (and Qs ready, iter 0)
        #pragma unroll
        for (int i = 0; i < 4; ++i) {
            int idx = t + i * 256;
            int row = idx >> 4;
            int col = (idx & 15) * 4;
            float4 kv = *(const float4*)&K[base + (size_t)(kt*64 + row) * HD_ + col];
            Ks[row][col+0] = kv.x; Ks[row][col+1] = kv.y;
            Ks[row][col+2] = kv.z; Ks[row][col+3] = kv.w;
            float4 vv = *(const float4*)&V[base + (size_t)(kt*64 + row) * HD_ + col];
            Vs[row][col+0] = vv.x; Vs[row][col+1] = vv.y;
            Vs[row][col+2] = vv.z; Vs[row][col+3] = vv.w;
        }
        __syncthreads();

        // scores: s[j] = dot(Qs[r], Ks[cq*16+j]) over 64 dims (Q pre-scaled)
        float s[16];
        #pragma unroll
        for (int j = 0; j < 16; ++j) s[j] = 0.f;
        for (int d = 0; d < 64; ++d) {
            float qv = Qs[r][d];
            #pragma unroll
            for (int j = 0; j < 16; ++j)
                s[j] += qv * Ks[cq*16 + j][d];
        }

        // online softmax
        float tmax = s[0];
        #pragma unroll
        for (int j = 1; j < 16; ++j) tmax = fmaxf(tmax, s[j]);
        tmax = fmaxf(tmax, __shfl_xor(tmax, 1));
        tmax = fmaxf(tmax, __shfl_xor(tmax, 2));
        float newm  = fmaxf(mrun, tmax);
        float alpha = __expf(mrun - newm);
        float p[16], rs = 0.f;
        #pragma unroll
        for (int j = 0; j < 16; ++j) { p[j] = __expf(s[j] - newm); rs += p[j]; }
        rs += __shfl_xor(rs, 1);
        rs += __shfl_xor(rs, 2);
        lrun = lrun * alpha + rs;
        mrun = newm;
        #pragma unroll
        for (int j = 0; j < 16; ++j) o[j] *= alpha;
        #pragma unroll
        for (int j = 0; j < 16; ++j) Ps[r][cq*16 + j] = p[j];
        __syncthreads();

        // PV: o[j] += sum_k Ps[r][k] * Vs[k][cq*16+j]
        for (int k = 0; k < 64; ++k) {
            float pv = Ps[r][k];
            #pragma unroll
            for (int j = 0; j < 16; ++j)
                o[j] += pv * Vs[k][cq*16 + j];
        }
    }

    // epilogue: normalize, write to [B,S,E]
    const float inv = 1.f / lrun;
    const int b = bh >> 4;      // bh = b*H + h, H=16
    const int h = bh & 15;
    #pragma unroll
    for (int j = 0; j < 16; ++j) {
        O[((size_t)(b * S_ + q0 + r)) * E_ + h * HD_ + cq*16 + j] = o[j] * inv;
    }
}

extern "C" void kernel_launch(void* const* d_in, const int* in_sizes, int n_in,
                              void* d_out, int out_size, void* d_ws, size_t ws_size,
                              hipStream_t stream) {
    const float* x  = (const float*)d_in[0];
    const float* Wq = (const float*)d_in[1];
    const float* bq = (const float*)d_in[2];
    const float* Wk = (const float*)d_in[3];
    const float* bk = (const float*)d_in[4];
    const float* Wv = (const float*)d_in[5];
    const float* bv = (const float*)d_in[6];
    const float* Wo = (const float*)d_in[7];
    const float* bo = (const float*)d_in[8];
    float* out = (float*)d_out;

    const size_t per = (size_t)B_ * H_ * S_ * HD_;   // 4,194,304 floats
    float* q  = (float*)d_ws;
    float* k  = q + per;
    float* v  = k + per;
    float* ao = v + per;

    const int M = B_ * S_;
    dim3 blk(256);
    dim3 gg(E_ / 64, M / 64);      // (16, 64)
    gemm_xwt<<<gg, blk, 0, stream>>>(x,  Wq, bq, q,  M, E_, E_, 1);
    gemm_xwt<<<gg, blk, 0, stream>>>(x,  Wk, bk, k,  M, E_, E_, 1);
    gemm_xwt<<<gg, blk, 0, stream>>>(x,  Wv, bv, v,  M, E_, E_, 1);

    dim3 ga(S_ / 64, B_ * H_);     // (32, 32)
    attn_fwd<<<ga, blk, 0, stream>>>(q, k, v, ao);

    gemm_xwt<<<gg, blk, 0, stream>>>(ao, Wo, bo, out, M, E_, E_, 0);
}

// Round 3
// 794.756 us; speedup vs baseline: 2.8732x; 2.8732x over previous
//
#include <hip/hip_runtime.h>
#include <hip/hip_bf16.h>

#define B_ 2
#define S_ 2048
#define E_ 1024
#define H_ 16
#define HD_ 64

typedef __attribute__((ext_vector_type(8))) short bf16x8;
typedef __attribute__((ext_vector_type(4))) float f32x4;
typedef __attribute__((ext_vector_type(4))) unsigned short u16x4;
typedef unsigned short ushort_t;

static __device__ __forceinline__ ushort_t f2bf(float f) {
    union { __hip_bfloat16 b; ushort_t u; } cv;
    cv.b = __float2bfloat16(f);
    return cv.u;
}

// ---------------------------------------------------------------------------
// GEMM: C = (A @ W^T + bias) * oscale
//   A: [M,K] fp32 row-major, W: [N,K] fp32 row-major, bias[N]
//   mode 0: fp32 C[m*N + n]
//   mode 1: bf16 C[((b*H + h)*S + s)*HD + d]  (scatter to [B,H,S,HD])
// ---------------------------------------------------------------------------
__global__ __launch_bounds__(256)
void gemm_xwt(const float* __restrict__ A, const float* __restrict__ W,
              const float* __restrict__ bias, void* __restrict__ Cout,
              int M, int N, int K, int mode, float oscale)
{
    __shared__ float As[64][33];
    __shared__ float Ws[64][33];
    const int t  = threadIdx.x;
    const int m0 = blockIdx.y * 64;
    const int n0 = blockIdx.x * 64;
    const int tr = t >> 4;
    const int tc = t & 15;

    float acc[4][4] = {};

    for (int k0 = 0; k0 < K; k0 += 32) {
        #pragma unroll
        for (int i = 0; i < 2; ++i) {
            int idx = t + i * 256;
            int row = idx >> 3;
            int col = (idx & 7) * 4;
            float4 av = *(const float4*)&A[(size_t)(m0 + row) * K + k0 + col];
            As[row][col+0] = av.x; As[row][col+1] = av.y;
            As[row][col+2] = av.z; As[row][col+3] = av.w;
            float4 wv = *(const float4*)&W[(size_t)(n0 + row) * K + k0 + col];
            Ws[row][col+0] = wv.x; Ws[row][col+1] = wv.y;
            Ws[row][col+2] = wv.z; Ws[row][col+3] = wv.w;
        }
        __syncthreads();

        #pragma unroll
        for (int kk = 0; kk < 32; ++kk) {
            float a[4], w[4];
            #pragma unroll
            for (int i = 0; i < 4; ++i) a[i] = As[tr + i*16][kk];
            #pragma unroll
            for (int j = 0; j < 4; ++j) w[j] = Ws[tc + j*16][kk];
            #pragma unroll
            for (int i = 0; i < 4; ++i)
                #pragma unroll
                for (int j = 0; j < 4; ++j)
                    acc[i][j] += a[i] * w[j];
        }
        __syncthreads();
    }

    #pragma unroll
    for (int i = 0; i < 4; ++i) {
        int m = m0 + tr + i*16;
        #pragma unroll
        for (int j = 0; j < 4; ++j) {
            int n = n0 + tc + j*16;
            float v = (acc[i][j] + bias[n]) * oscale;
            if (mode == 0) {
                ((float*)Cout)[(size_t)m * N + n] = v;
            } else {
                int b = m >> 11, s = m & (S_ - 1);
                int h = n >> 6,  d = n & (HD_ - 1);
                ((__hip_bfloat16*)Cout)[(((size_t)(b * H_ + h)) * S_ + s) * HD_ + d] =
                    __float2bfloat16(v);
            }
        }
    }
}

// ---------------------------------------------------------------------------
// MFMA flash attention, bf16 inputs, fp32 softmax/accum.
//   Q,K,V: bf16 [B,H,S,HD] (Q pre-scaled by 1/8). O: fp32 [B,S,E].
//   Block: 256 thr = 4 waves. Q-tile 64 rows (16/wave); KV tiles of 64,
//   double-buffered. Swapped QK^T (S^T = K Q^T) so per-lane softmax state is
//   scalar (q = lane&15). PV computed as O^T = V^T P^T with V staged
//   transposed. All LDS tiles [64][64] bf16 with 16B-chunk XOR swizzle
//   (chunk ^= row&7) -> conflict-free ds_read_b128 / ds_write_b128.
// ---------------------------------------------------------------------------
__global__ __launch_bounds__(256)
void attn_mfma(const ushort_t* __restrict__ Qg, const ushort_t* __restrict__ Kg,
               const ushort_t* __restrict__ Vg, float* __restrict__ O)
{
    __shared__ ushort_t KsT[2][64][64];   // K tile: [kv][d]
    __shared__ ushort_t VtT[2][64][64];   // V tile transposed: [d][kv]
    __shared__ ushort_t Qs[64][64];       // Q tile: [q][d]
    __shared__ ushort_t Ps[4][16][64];    // per-wave P: [q][kv]

    const int t    = threadIdx.x;
    const int w    = t >> 6;
    const int lane = t & 63;
    const int g    = lane >> 4;    // 0..3
    const int qi   = lane & 15;    // q column (and row-within-16 for A-frags)
    const int sw   = qi & 7;       // row-XOR swizzle key (row&7 == qi&7 for all tiles)
    const int bh   = blockIdx.y;
    const int q0   = blockIdx.x * 64;
    const size_t base = (size_t)bh * S_ * HD_;

    // ---- stage Q tile (swizzled) + K/V tile 0
    #pragma unroll
    for (int it = 0; it < 2; ++it) {
        int idx = t + it * 256;
        int row = idx >> 3, c8 = idx & 7;
        uint4 qv = *(const uint4*)&Qg[base + (size_t)(q0 + row) * HD_ + c8 * 8];
        *(uint4*)&Qs[row][8 * (c8 ^ (row & 7))] = qv;
        uint4 kv = *(const uint4*)&Kg[base + (size_t)(row) * HD_ + c8 * 8];
        *(uint4*)&KsT[0][row][8 * (c8 ^ (row & 7))] = kv;
    }
    {
        const int kvg = t >> 4, dg = t & 15;
        u16x4 vv[4];
        #pragma unroll
        for (int j = 0; j < 4; ++j)
            vv[j] = *(const u16x4*)&Vg[base + (size_t)(kvg * 4 + j) * HD_ + dg * 4];
        #pragma unroll
        for (int i = 0; i < 4; ++i) {
            int d = dg * 4 + i;
            u16x4 wvec = { vv[0][i], vv[1][i], vv[2][i], vv[3][i] };
            *(u16x4*)&VtT[0][d][8 * ((kvg >> 1) ^ (d & 7)) + 4 * (kvg & 1)] = wvec;
        }
    }
    __syncthreads();

    // ---- per-wave Q fragments (B-operand), loaded once
    const bf16x8 qf0 = *(const bf16x8*)&Qs[w * 16 + qi][8 * ((0 + g) ^ sw)];
    const bf16x8 qf1 = *(const bf16x8*)&Qs[w * 16 + qi][8 * ((4 + g) ^ sw)];

    float m_run = -3.0e38f, l_run = 0.f;
    f32x4 oacc[4];
    #pragma unroll
    for (int rb = 0; rb < 4; ++rb) oacc[rb] = (f32x4){0.f, 0.f, 0.f, 0.f};

    for (int tile = 0; tile < S_ / 64; ++tile) {
        const int cur = tile & 1;

        // prefetch next tile into registers (loads issued before compute)
        uint4 kpre[2];
        u16x4 vpre[4];
        const int kvg = t >> 4, dg = t & 15;
        if (tile < S_ / 64 - 1) {
            const size_t nb = base + (size_t)(tile + 1) * 64 * HD_;
            #pragma unroll
            for (int it = 0; it < 2; ++it) {
                int idx = t + it * 256;
                int row = idx >> 3, c8 = idx & 7;
                kpre[it] = *(const uint4*)&Kg[nb + (size_t)row * HD_ + c8 * 8];
            }
            #pragma unroll
            for (int j = 0; j < 4; ++j)
                vpre[j] = *(const u16x4*)&Vg[nb + (size_t)(kvg * 4 + j) * HD_ + dg * 4];
        }

        // ---- QK^T -> S^T (4 kv-row blocks x 16 q)
        f32x4 sacc[4];
        #pragma unroll
        for (int rb = 0; rb < 4; ++rb) {
            bf16x8 ka0 = *(const bf16x8*)&KsT[cur][rb * 16 + qi][8 * ((0 + g) ^ sw)];
            bf16x8 ka1 = *(const bf16x8*)&KsT[cur][rb * 16 + qi][8 * ((4 + g) ^ sw)];
            f32x4 z = (f32x4){0.f, 0.f, 0.f, 0.f};
            z = __builtin_amdgcn_mfma_f32_16x16x32_bf16(ka0, qf0, z, 0, 0, 0);
            z = __builtin_amdgcn_mfma_f32_16x16x32_bf16(ka1, qf1, z, 0, 0, 0);
            sacc[rb] = z;
        }

        // ---- online softmax: lane owns q=qi; 16 kv vals here, reduce over g
        float smax = sacc[0][0];
        #pragma unroll
        for (int rb = 0; rb < 4; ++rb)
            #pragma unroll
            for (int r = 0; r < 4; ++r) smax = fmaxf(smax, sacc[rb][r]);
        smax = fmaxf(smax, __shfl_xor(smax, 16));
        smax = fmaxf(smax, __shfl_xor(smax, 32));
        const float mnew  = fmaxf(m_run, smax);
        const float alpha = __expf(m_run - mnew);
        float psum = 0.f;
        ushort_t pb[4][4];
        #pragma unroll
        for (int rb = 0; rb < 4; ++rb)
            #pragma unroll
            for (int r = 0; r < 4; ++r) {
                float p = __expf(sacc[rb][r] - mnew);
                psum += p;
                pb[rb][r] = f2bf(p);
            }
        psum += __shfl_xor(psum, 16);
        psum += __shfl_xor(psum, 32);
        l_run = l_run * alpha + psum;
        m_run = mnew;
        #pragma unroll
        for (int rb = 0; rb < 4; ++rb)
            #pragma unroll
            for (int r = 0; r < 4; ++r) oacc[rb][r] *= alpha;

        // ---- write P (bf16, [q][kv], swizzled); same-wave RAW -> no barrier
        #pragma unroll
        for (int rb = 0; rb < 4; ++rb) {
            u16x4 pv = { pb[rb][0], pb[rb][1], pb[rb][2], pb[rb][3] };
            int ch = (2 * rb + (g >> 1)) ^ sw;
            *(u16x4*)&Ps[w][qi][8 * ch + 4 * (g & 1)] = pv;
        }

        // ---- PV: O^T += V^T P^T
        #pragma unroll
        for (int kc = 0; kc < 2; ++kc) {
            bf16x8 pf = *(const bf16x8*)&Ps[w][qi][8 * ((4 * kc + g) ^ sw)];
            #pragma unroll
            for (int rb = 0; rb < 4; ++rb) {
                bf16x8 va = *(const bf16x8*)&VtT[cur][rb * 16 + qi][8 * ((4 * kc + g) ^ sw)];
                oacc[rb] = __builtin_amdgcn_mfma_f32_16x16x32_bf16(va, pf, oacc[rb], 0, 0, 0);
            }
        }

        __syncthreads();   // everyone done reading buf[cur]
        if (tile < S_ / 64 - 1) {
            #pragma unroll
            for (int it = 0; it < 2; ++it) {
                int idx = t + it * 256;
                int row = idx >> 3, c8 = idx & 7;
                *(uint4*)&KsT[cur ^ 1][row][8 * (c8 ^ (row & 7))] = kpre[it];
            }
            #pragma unroll
            for (int i = 0; i < 4; ++i) {
                int d = dg * 4 + i;
                u16x4 wvec = { vpre[0][i], vpre[1][i], vpre[2][i], vpre[3][i] };
                *(u16x4*)&VtT[cur ^ 1][d][8 * ((kvg >> 1) ^ (d & 7)) + 4 * (kvg & 1)] = wvec;
            }
            __syncthreads();   // writes visible before next compute
        }
    }

    // ---- epilogue: O^T lane layout -> global [B,S,E]
    const float inv = 1.f / l_run;
    const int b = bh >> 4, h = bh & 15;
    const size_t orow = (size_t)(b * S_ + q0 + w * 16 + qi) * E_ + h * HD_;
    #pragma unroll
    for (int rb = 0; rb < 4; ++rb) {
        float4 ov;
        ov.x = oacc[rb][0] * inv;
        ov.y = oacc[rb][1] * inv;
        ov.z = oacc[rb][2] * inv;
        ov.w = oacc[rb][3] * inv;
        *(float4*)&O[orow + rb * 16 + g * 4] = ov;
    }
}

extern "C" void kernel_launch(void* const* d_in, const int* in_sizes, int n_in,
                              void* d_out, int out_size, void* d_ws, size_t ws_size,
                              hipStream_t stream) {
    const float* x  = (const float*)d_in[0];
    const float* Wq = (const float*)d_in[1];
    const float* bq = (const float*)d_in[2];
    const float* Wk = (const float*)d_in[3];
    const float* bk = (const float*)d_in[4];
    const float* Wv = (const float*)d_in[5];
    const float* bv = (const float*)d_in[6];
    const float* Wo = (const float*)d_in[7];
    const float* bo = (const float*)d_in[8];
    float* out = (float*)d_out;

    const size_t per = (size_t)B_ * H_ * S_ * HD_;   // 4,194,304 elements
    ushort_t* qws = (ushort_t*)d_ws;                 // bf16 [B,H,S,HD]
    ushort_t* kws = qws + per;
    ushort_t* vws = kws + per;
    float*    ao  = (float*)(vws + per);             // fp32 [B,S,E]

    const int M = B_ * S_;
    dim3 blk(256);
    dim3 gg(E_ / 64, M / 64);
    gemm_xwt<<<gg, blk, 0, stream>>>(x, Wq, bq, qws, M, E_, E_, 1, 0.125f);
    gemm_xwt<<<gg, blk, 0, stream>>>(x, Wk, bk, kws, M, E_, E_, 1, 1.0f);
    gemm_xwt<<<gg, blk, 0, stream>>>(x, Wv, bv, vws, M, E_, E_, 1, 1.0f);

    dim3 ga(S_ / 64, B_ * H_);
    attn_mfma<<<ga, blk, 0, stream>>>(qws, kws, vws, ao);

    gemm_xwt<<<gg, blk, 0, stream>>>(ao, Wo, bo, out, M, E_, E_, 0, 1.0f);
}

// Round 4
// 483.736 us; speedup vs baseline: 4.7206x; 1.6430x over previous
//
#include <hip/hip_runtime.h>
#include <hip/hip_bf16.h>

#define B_ 2
#define S_ 2048
#define E_ 1024
#define H_ 16
#define HD_ 64
#define M_ (B_ * S_)   // 4096

typedef __attribute__((ext_vector_type(8))) short bf16x8;
typedef __attribute__((ext_vector_type(4))) float f32x4;
typedef __attribute__((ext_vector_type(4))) unsigned short u16x4;
typedef unsigned short ushort_t;

static __device__ __forceinline__ ushort_t f2bf(float f) {
    union { __hip_bfloat16 b; ushort_t u; } cv;
    cv.b = __float2bfloat16(f);
    return cv.u;
}
static __device__ __forceinline__ float bf2f(ushort_t u) {
    union { unsigned int i; float f; } cv;
    cv.i = ((unsigned int)u) << 16;
    return cv.f;
}

// ---------------------------------------------------------------------------
// Fused conversion: x,Wq,Wk,Wv -> bf16; Wo -> (hi,lo) bf16 split.
// Unit = one float4 (4 elems). Regions: x:1M, Wq/Wk/Wv/Wo: 256K units each.
// ---------------------------------------------------------------------------
__global__ __launch_bounds__(256)
void conv_pack(const float* __restrict__ x,  const float* __restrict__ Wq,
               const float* __restrict__ Wk, const float* __restrict__ Wv,
               const float* __restrict__ Wo,
               ushort_t* __restrict__ xb,  ushort_t* __restrict__ Wqb,
               ushort_t* __restrict__ Wkb, ushort_t* __restrict__ Wvb,
               ushort_t* __restrict__ Wohi, ushort_t* __restrict__ Wolo)
{
    const int NX = (B_ * S_ * E_) / 4;   // 1,048,576
    const int NW = (E_ * E_) / 4;        // 262,144
    const int total = NX + 4 * NW;
    for (int u = blockIdx.x * blockDim.x + threadIdx.x; u < total;
         u += gridDim.x * blockDim.x) {
        if (u < NX) {
            float4 v = ((const float4*)x)[u];
            u16x4 o = { f2bf(v.x), f2bf(v.y), f2bf(v.z), f2bf(v.w) };
            ((u16x4*)xb)[u] = o;
        } else if (u < NX + 3 * NW) {
            int r = (u - NX) >> 18;          // NW = 2^18
            int i = (u - NX) & (NW - 1);
            const float* src = (r == 0) ? Wq : ((r == 1) ? Wk : Wv);
            ushort_t*    dst = (r == 0) ? Wqb : ((r == 1) ? Wkb : Wvb);
            float4 v = ((const float4*)src)[i];
            u16x4 o = { f2bf(v.x), f2bf(v.y), f2bf(v.z), f2bf(v.w) };
            ((u16x4*)dst)[i] = o;
        } else {
            int i = u - NX - 3 * NW;
            float4 v = ((const float4*)Wo)[i];
            u16x4 hv, lv;
            float vv[4] = { v.x, v.y, v.z, v.w };
            #pragma unroll
            for (int r = 0; r < 4; ++r) {
                ushort_t hb = f2bf(vv[r]);
                hv[r] = hb;
                lv[r] = f2bf(vv[r] - bf2f(hb));
            }
            ((u16x4*)Wohi)[i] = hv;
            ((u16x4*)Wolo)[i] = lv;
        }
    }
}

// ---------------------------------------------------------------------------
// MFMA GEMM: C = (A @ W^T + bias) * oscale, A:[M,K] bf16, W:[N,K] bf16.
// SPLIT=0: single-plane inputs, bf16 output scattered to [B,H,S,HD].
// SPLIT=1: A=(A0+A1), W=(W0+W1) hi/lo planes, 3-pass MFMA (hi*hi+hi*lo+lo*hi),
//          fp32 row-major output (fp32-quality result).
// BM=128, BN=64, BK=64; 256 thr = 4 waves (2x2), wave tile 64x32.
// LDS tiles [row][64] bf16, 16B-chunk XOR swizzle (chunk ^= row&7) ->
// conflict-free ds_read_b128/ds_write_b128. Register prefetch, single buffer.
// ---------------------------------------------------------------------------
template<int SPLIT>
__global__ __launch_bounds__(256)
void gemm_mfma(const ushort_t* __restrict__ A0, const ushort_t* __restrict__ A1,
               const ushort_t* __restrict__ W0, const ushort_t* __restrict__ W1,
               const float* __restrict__ bias, void* __restrict__ Cout,
               float oscale)
{
    constexpr int NP = SPLIT + 1;
    __shared__ ushort_t As[NP][128][64];
    __shared__ ushort_t Ws[NP][64][64];

    const int K = E_;
    const int t = threadIdx.x;
    const int w = t >> 6, lane = t & 63;
    const int g = lane >> 4, qi = lane & 15, sw = qi & 7;
    const int wr = w >> 1, wc = w & 1;
    const int m0 = blockIdx.y * 128, n0 = blockIdx.x * 64;

    const ushort_t* Ap[NP];
    const ushort_t* Wp[NP];
    Ap[0] = A0; Wp[0] = W0;
    if (SPLIT) { Ap[1] = A1; Wp[1] = W1; }

    uint4 apre[NP][4];
    uint4 wpre[NP][2];

    auto load_tile = [&](int kt) {
        const int k0 = kt * 64;
        #pragma unroll
        for (int p = 0; p < NP; ++p) {
            #pragma unroll
            for (int it = 0; it < 4; ++it) {
                int idx = t + it * 256, row = idx >> 3, c8 = idx & 7;
                apre[p][it] = *(const uint4*)&Ap[p][(size_t)(m0 + row) * K + k0 + c8 * 8];
            }
            #pragma unroll
            for (int it = 0; it < 2; ++it) {
                int idx = t + it * 256, row = idx >> 3, c8 = idx & 7;
                wpre[p][it] = *(const uint4*)&Wp[p][(size_t)(n0 + row) * K + k0 + c8 * 8];
            }
        }
    };
    auto write_tile = [&]() {
        #pragma unroll
        for (int p = 0; p < NP; ++p) {
            #pragma unroll
            for (int it = 0; it < 4; ++it) {
                int idx = t + it * 256, row = idx >> 3, c8 = idx & 7;
                *(uint4*)&As[p][row][8 * (c8 ^ (row & 7))] = apre[p][it];
            }
            #pragma unroll
            for (int it = 0; it < 2; ++it) {
                int idx = t + it * 256, row = idx >> 3, c8 = idx & 7;
                *(uint4*)&Ws[p][row][8 * (c8 ^ (row & 7))] = wpre[p][it];
            }
        }
    };

    f32x4 acc[4][2];
    #pragma unroll
    for (int i = 0; i < 4; ++i)
        #pragma unroll
        for (int j = 0; j < 2; ++j) acc[i][j] = (f32x4){0.f, 0.f, 0.f, 0.f};

    load_tile(0);
    write_tile();
    __syncthreads();

    const int NT = K / 64;   // 16
    for (int kt = 0; kt < NT; ++kt) {
        if (kt + 1 < NT) load_tile(kt + 1);

        #pragma unroll
        for (int h = 0; h < 2; ++h) {
            bf16x8 af[NP][4], wf[NP][2];
            #pragma unroll
            for (int p = 0; p < NP; ++p) {
                #pragma unroll
                for (int i = 0; i < 4; ++i)
                    af[p][i] = *(const bf16x8*)&As[p][wr * 64 + i * 16 + qi]
                                                  [8 * ((h * 4 + g) ^ sw)];
                #pragma unroll
                for (int j = 0; j < 2; ++j)
                    wf[p][j] = *(const bf16x8*)&Ws[p][wc * 32 + j * 16 + qi]
                                                  [8 * ((h * 4 + g) ^ sw)];
            }
            #pragma unroll
            for (int i = 0; i < 4; ++i)
                #pragma unroll
                for (int j = 0; j < 2; ++j) {
                    acc[i][j] = __builtin_amdgcn_mfma_f32_16x16x32_bf16(
                        af[0][i], wf[0][j], acc[i][j], 0, 0, 0);
                    if (SPLIT) {
                        acc[i][j] = __builtin_amdgcn_mfma_f32_16x16x32_bf16(
                            af[0][i], wf[1][j], acc[i][j], 0, 0, 0);
                        acc[i][j] = __builtin_amdgcn_mfma_f32_16x16x32_bf16(
                            af[1][i], wf[0][j], acc[i][j], 0, 0, 0);
                    }
                }
        }
        __syncthreads();
        if (kt + 1 < NT) {
            write_tile();
            __syncthreads();
        }
    }

    // epilogue
    float bj[2];
    #pragma unroll
    for (int j = 0; j < 2; ++j) bj[j] = bias[n0 + wc * 32 + j * 16 + qi];

    #pragma unroll
    for (int i = 0; i < 4; ++i)
        #pragma unroll
        for (int j = 0; j < 2; ++j) {
            const int n = n0 + wc * 32 + j * 16 + qi;
            #pragma unroll
            for (int r = 0; r < 4; ++r) {
                const int m = m0 + wr * 64 + i * 16 + g * 4 + r;
                float v = (acc[i][j][r] + bj[j]) * oscale;
                if (SPLIT == 0) {
                    int b = m >> 11, s = m & (S_ - 1);
                    int h = n >> 6,  d = n & (HD_ - 1);
                    ((ushort_t*)Cout)[(((size_t)(b * H_ + h)) * S_ + s) * HD_ + d] = f2bf(v);
                } else {
                    ((float*)Cout)[(size_t)m * E_ + n] = v;
                }
            }
        }
}

// ---------------------------------------------------------------------------
// MFMA flash attention, bf16 in, fp32 softmax/accum, hi/lo bf16 split output.
// (same verified structure as Round 3; epilogue now emits O = Ohi + Olo)
// ---------------------------------------------------------------------------
__global__ __launch_bounds__(256)
void attn_mfma(const ushort_t* __restrict__ Qg, const ushort_t* __restrict__ Kg,
               const ushort_t* __restrict__ Vg,
               ushort_t* __restrict__ Ohi, ushort_t* __restrict__ Olo)
{
    __shared__ ushort_t KsT[2][64][64];   // K tile: [kv][d]
    __shared__ ushort_t VtT[2][64][64];   // V tile transposed: [d][kv]
    __shared__ ushort_t Qs[64][64];       // Q tile: [q][d]
    __shared__ ushort_t Ps[4][16][64];    // per-wave P: [q][kv]

    const int t    = threadIdx.x;
    const int w    = t >> 6;
    const int lane = t & 63;
    const int g    = lane >> 4;
    const int qi   = lane & 15;
    const int sw   = qi & 7;
    const int bh   = blockIdx.y;
    const int q0   = blockIdx.x * 64;
    const size_t base = (size_t)bh * S_ * HD_;

    #pragma unroll
    for (int it = 0; it < 2; ++it) {
        int idx = t + it * 256;
        int row = idx >> 3, c8 = idx & 7;
        uint4 qv = *(const uint4*)&Qg[base + (size_t)(q0 + row) * HD_ + c8 * 8];
        *(uint4*)&Qs[row][8 * (c8 ^ (row & 7))] = qv;
        uint4 kv = *(const uint4*)&Kg[base + (size_t)(row) * HD_ + c8 * 8];
        *(uint4*)&KsT[0][row][8 * (c8 ^ (row & 7))] = kv;
    }
    {
        const int kvg = t >> 4, dg = t & 15;
        u16x4 vv[4];
        #pragma unroll
        for (int j = 0; j < 4; ++j)
            vv[j] = *(const u16x4*)&Vg[base + (size_t)(kvg * 4 + j) * HD_ + dg * 4];
        #pragma unroll
        for (int i = 0; i < 4; ++i) {
            int d = dg * 4 + i;
            u16x4 wvec = { vv[0][i], vv[1][i], vv[2][i], vv[3][i] };
            *(u16x4*)&VtT[0][d][8 * ((kvg >> 1) ^ (d & 7)) + 4 * (kvg & 1)] = wvec;
        }
    }
    __syncthreads();

    const bf16x8 qf0 = *(const bf16x8*)&Qs[w * 16 + qi][8 * ((0 + g) ^ sw)];
    const bf16x8 qf1 = *(const bf16x8*)&Qs[w * 16 + qi][8 * ((4 + g) ^ sw)];

    float m_run = -3.0e38f, l_run = 0.f;
    f32x4 oacc[4];
    #pragma unroll
    for (int rb = 0; rb < 4; ++rb) oacc[rb] = (f32x4){0.f, 0.f, 0.f, 0.f};

    for (int tile = 0; tile < S_ / 64; ++tile) {
        const int cur = tile & 1;

        uint4 kpre[2];
        u16x4 vpre[4];
        const int kvg = t >> 4, dg = t & 15;
        if (tile < S_ / 64 - 1) {
            const size_t nb = base + (size_t)(tile + 1) * 64 * HD_;
            #pragma unroll
            for (int it = 0; it < 2; ++it) {
                int idx = t + it * 256;
                int row = idx >> 3, c8 = idx & 7;
                kpre[it] = *(const uint4*)&Kg[nb + (size_t)row * HD_ + c8 * 8];
            }
            #pragma unroll
            for (int j = 0; j < 4; ++j)
                vpre[j] = *(const u16x4*)&Vg[nb + (size_t)(kvg * 4 + j) * HD_ + dg * 4];
        }

        f32x4 sacc[4];
        #pragma unroll
        for (int rb = 0; rb < 4; ++rb) {
            bf16x8 ka0 = *(const bf16x8*)&KsT[cur][rb * 16 + qi][8 * ((0 + g) ^ sw)];
            bf16x8 ka1 = *(const bf16x8*)&KsT[cur][rb * 16 + qi][8 * ((4 + g) ^ sw)];
            f32x4 z = (f32x4){0.f, 0.f, 0.f, 0.f};
            z = __builtin_amdgcn_mfma_f32_16x16x32_bf16(ka0, qf0, z, 0, 0, 0);
            z = __builtin_amdgcn_mfma_f32_16x16x32_bf16(ka1, qf1, z, 0, 0, 0);
            sacc[rb] = z;
        }

        float smax = sacc[0][0];
        #pragma unroll
        for (int rb = 0; rb < 4; ++rb)
            #pragma unroll
            for (int r = 0; r < 4; ++r) smax = fmaxf(smax, sacc[rb][r]);
        smax = fmaxf(smax, __shfl_xor(smax, 16));
        smax = fmaxf(smax, __shfl_xor(smax, 32));
        const float mnew  = fmaxf(m_run, smax);
        const float alpha = __expf(m_run - mnew);
        float psum = 0.f;
        ushort_t pb[4][4];
        #pragma unroll
        for (int rb = 0; rb < 4; ++rb)
            #pragma unroll
            for (int r = 0; r < 4; ++r) {
                float p = __expf(sacc[rb][r] - mnew);
                psum += p;
                pb[rb][r] = f2bf(p);
            }
        psum += __shfl_xor(psum, 16);
        psum += __shfl_xor(psum, 32);
        l_run = l_run * alpha + psum;
        m_run = mnew;
        #pragma unroll
        for (int rb = 0; rb < 4; ++rb)
            #pragma unroll
            for (int r = 0; r < 4; ++r) oacc[rb][r] *= alpha;

        #pragma unroll
        for (int rb = 0; rb < 4; ++rb) {
            u16x4 pv = { pb[rb][0], pb[rb][1], pb[rb][2], pb[rb][3] };
            int ch = (2 * rb + (g >> 1)) ^ sw;
            *(u16x4*)&Ps[w][qi][8 * ch + 4 * (g & 1)] = pv;
        }

        #pragma unroll
        for (int kc = 0; kc < 2; ++kc) {
            bf16x8 pf = *(const bf16x8*)&Ps[w][qi][8 * ((4 * kc + g) ^ sw)];
            #pragma unroll
            for (int rb = 0; rb < 4; ++rb) {
                bf16x8 va = *(const bf16x8*)&VtT[cur][rb * 16 + qi][8 * ((4 * kc + g) ^ sw)];
                oacc[rb] = __builtin_amdgcn_mfma_f32_16x16x32_bf16(va, pf, oacc[rb], 0, 0, 0);
            }
        }

        __syncthreads();
        if (tile < S_ / 64 - 1) {
            #pragma unroll
            for (int it = 0; it < 2; ++it) {
                int idx = t + it * 256;
                int row = idx >> 3, c8 = idx & 7;
                *(uint4*)&KsT[cur ^ 1][row][8 * (c8 ^ (row & 7))] = kpre[it];
            }
            #pragma unroll
            for (int i = 0; i < 4; ++i) {
                int d = dg * 4 + i;
                u16x4 wvec = { vpre[0][i], vpre[1][i], vpre[2][i], vpre[3][i] };
                *(u16x4*)&VtT[cur ^ 1][d][8 * ((kvg >> 1) ^ (d & 7)) + 4 * (kvg & 1)] = wvec;
            }
            __syncthreads();
        }
    }

    const float inv = 1.f / l_run;
    const int b = bh >> 4, h = bh & 15;
    const size_t orow = (size_t)(b * S_ + q0 + w * 16 + qi) * E_ + h * HD_;
    #pragma unroll
    for (int rb = 0; rb < 4; ++rb) {
        u16x4 hv, lv;
        #pragma unroll
        for (int r = 0; r < 4; ++r) {
            float v = oacc[rb][r] * inv;
            ushort_t hb = f2bf(v);
            hv[r] = hb;
            lv[r] = f2bf(v - bf2f(hb));
        }
        *(u16x4*)&Ohi[orow + rb * 16 + g * 4] = hv;
        *(u16x4*)&Olo[orow + rb * 16 + g * 4] = lv;
    }
}

extern "C" void kernel_launch(void* const* d_in, const int* in_sizes, int n_in,
                              void* d_out, int out_size, void* d_ws, size_t ws_size,
                              hipStream_t stream) {
    const float* x  = (const float*)d_in[0];
    const float* Wq = (const float*)d_in[1];
    const float* bq = (const float*)d_in[2];
    const float* Wk = (const float*)d_in[3];
    const float* bk = (const float*)d_in[4];
    const float* Wv = (const float*)d_in[5];
    const float* bv = (const float*)d_in[6];
    const float* Wo = (const float*)d_in[7];
    const float* bo = (const float*)d_in[8];
    float* out = (float*)d_out;

    const size_t T4 = (size_t)B_ * S_ * E_;   // 4,194,304
    const size_t W1 = (size_t)E_ * E_;        // 1,048,576
    ushort_t* xb   = (ushort_t*)d_ws;
    ushort_t* Wqb  = xb   + T4;
    ushort_t* Wkb  = Wqb  + W1;
    ushort_t* Wvb  = Wkb  + W1;
    ushort_t* Wohi = Wvb  + W1;
    ushort_t* Wolo = Wohi + W1;
    ushort_t* qws  = Wolo + W1;
    ushort_t* kws  = qws  + T4;
    ushort_t* vws  = kws  + T4;
    ushort_t* aohi = vws  + T4;
    ushort_t* aolo = aohi + T4;

    dim3 blk(256);
    conv_pack<<<2048, blk, 0, stream>>>(x, Wq, Wk, Wv, Wo,
                                        xb, Wqb, Wkb, Wvb, Wohi, Wolo);

    dim3 gg(E_ / 64, M_ / 128);   // (16, 32)
    gemm_mfma<0><<<gg, blk, 0, stream>>>(xb, nullptr, Wqb, nullptr, bq, qws, 0.125f);
    gemm_mfma<0><<<gg, blk, 0, stream>>>(xb, nullptr, Wkb, nullptr, bk, kws, 1.0f);
    gemm_mfma<0><<<gg, blk, 0, stream>>>(xb, nullptr, Wvb, nullptr, bv, vws, 1.0f);

    dim3 ga(S_ / 64, B_ * H_);    // (32, 32)
    attn_mfma<<<ga, blk, 0, stream>>>(qws, kws, vws, aohi, aolo);

    gemm_mfma<1><<<gg, blk, 0, stream>>>(aohi, aolo, Wohi, Wolo, bo, out, 1.0f);
}

// Round 5
// 280.815 us; speedup vs baseline: 8.1318x; 1.7226x over previous
//
#include <hip/hip_runtime.h>
#include <hip/hip_bf16.h>

#define B_ 2
#define S_ 2048
#define E_ 1024
#define H_ 16
#define HD_ 64
#define M_ (B_ * S_)   // 4096

typedef __attribute__((ext_vector_type(8))) short bf16x8;
typedef __attribute__((ext_vector_type(4))) float f32x4;
typedef __attribute__((ext_vector_type(4))) unsigned short u16x4;
typedef unsigned short ushort_t;

static __device__ __forceinline__ ushort_t f2bf(float f) {
    union { __hip_bfloat16 b; ushort_t u; } cv;
    cv.b = __float2bfloat16(f);
    return cv.u;
}
static __device__ __forceinline__ float bf2f(ushort_t u) {
    union { unsigned int i; float f; } cv;
    cv.i = ((unsigned int)u) << 16;
    return cv.f;
}
// async global->LDS, 16B per lane; LDS dest = wave-uniform base + lane*16
static __device__ __forceinline__ void gl2lds16(const ushort_t* g, ushort_t* l) {
    __builtin_amdgcn_global_load_lds(
        (const __attribute__((address_space(1))) unsigned int*)g,
        (__attribute__((address_space(3))) unsigned int*)l,
        16, 0, 0);
}

// ---------------------------------------------------------------------------
// Fused conversion: x,Wq,Wk,Wv -> bf16; Wo -> (hi,lo) bf16 split; bias concat.
// ---------------------------------------------------------------------------
__global__ __launch_bounds__(256)
void conv_pack(const float* __restrict__ x,  const float* __restrict__ Wq,
               const float* __restrict__ Wk, const float* __restrict__ Wv,
               const float* __restrict__ Wo, const float* __restrict__ bq,
               const float* __restrict__ bk, const float* __restrict__ bv,
               ushort_t* __restrict__ xb,  ushort_t* __restrict__ Wqb,
               ushort_t* __restrict__ Wkb, ushort_t* __restrict__ Wvb,
               ushort_t* __restrict__ Wohi, ushort_t* __restrict__ Wolo,
               float* __restrict__ bcat)
{
    const int NX = (B_ * S_ * E_) / 4;   // 1,048,576
    const int NW = (E_ * E_) / 4;        // 262,144
    const int total = NX + 4 * NW + 768;
    for (int u = blockIdx.x * blockDim.x + threadIdx.x; u < total;
         u += gridDim.x * blockDim.x) {
        if (u < NX) {
            float4 v = ((const float4*)x)[u];
            u16x4 o = { f2bf(v.x), f2bf(v.y), f2bf(v.z), f2bf(v.w) };
            ((u16x4*)xb)[u] = o;
        } else if (u < NX + 3 * NW) {
            int r = (u - NX) >> 18;          // NW = 2^18
            int i = (u - NX) & (NW - 1);
            const float* src = (r == 0) ? Wq : ((r == 1) ? Wk : Wv);
            ushort_t*    dst = (r == 0) ? Wqb : ((r == 1) ? Wkb : Wvb);
            float4 v = ((const float4*)src)[i];
            u16x4 o = { f2bf(v.x), f2bf(v.y), f2bf(v.z), f2bf(v.w) };
            ((u16x4*)dst)[i] = o;
        } else if (u < NX + 4 * NW) {
            int i = u - NX - 3 * NW;
            float4 v = ((const float4*)Wo)[i];
            u16x4 hv, lv;
            float vv[4] = { v.x, v.y, v.z, v.w };
            #pragma unroll
            for (int r = 0; r < 4; ++r) {
                ushort_t hb = f2bf(vv[r]);
                hv[r] = hb;
                lv[r] = f2bf(vv[r] - bf2f(hb));
            }
            ((u16x4*)Wohi)[i] = hv;
            ((u16x4*)Wolo)[i] = lv;
        } else {
            int i = u - NX - 4 * NW;         // 0..767
            int r = i >> 8, ii = i & 255;
            const float* src = (r == 0) ? bq : ((r == 1) ? bk : bv);
            ((float4*)bcat)[r * 256 + ii] = ((const float4*)src)[ii];
        }
    }
}

// ---------------------------------------------------------------------------
// Unified MFMA GEMM. BM=128 BN=64 BK=64, 4 waves (2x2), wave tile 64x32.
// global_load_lds (16B) staging, pre-swizzled global source (XOR c8^(row&7)
// is an involution; LDS dest linear; fragment reads swizzled). Double-
// buffered LDS (48 KB), ONE barrier per K-tile, setprio around MFMA.
// MODE 0: fused QKV. A=xb [4096,1024]; N=3072 in 3 regions (Wq/Wk/Wv);
//         bias=bcat[3072]; out scattered bf16 to q/k/v [B,H,S,HD]; q scaled.
// MODE 1: output projection, fp32-quality via hi/lo split = plain GEMM with
//         K'=3072: kt 0-15 Ah*Wh, 16-31 Ah*Wl, 32-47 Al*Wh. fp32 out + bias.
// ---------------------------------------------------------------------------
template<int MODE>
__global__ __launch_bounds__(256)
void gemm_mfma(const ushort_t* __restrict__ Aa, const ushort_t* __restrict__ Ab,
               const ushort_t* __restrict__ W0p, const ushort_t* __restrict__ W1p,
               const ushort_t* __restrict__ W2p, const float* __restrict__ bias,
               ushort_t* __restrict__ O0, ushort_t* __restrict__ O1,
               ushort_t* __restrict__ O2, float* __restrict__ Of)
{
    constexpr int NBX = MODE ? 16 : 48;
    constexpr int NT  = MODE ? 48 : 16;
    __shared__ ushort_t As[2][128 * 64];
    __shared__ ushort_t Ws[2][64 * 64];

    // bijective XCD swizzle (nwg % 8 == 0)
    const int nwg = NBX * (M_ / 128);
    const int b0  = blockIdx.x;
    const int bid = (b0 & 7) * (nwg >> 3) + (b0 >> 3);
    const int bx = bid % NBX, by = bid / NBX;
    const int m0 = by * 128, n0 = bx * 64;

    const int t = threadIdx.x;
    const int w = t >> 6, lane = t & 63;
    const int g = lane >> 4, qi = lane & 15, sw = qi & 7;
    const int wr = w >> 1, wc = w & 1;

    const ushort_t* WA;
    int nw0;
    int region = 0;
    if (MODE == 0) {
        region = n0 >> 10;
        WA = (region == 0) ? W0p : (region == 1) ? W1p : W2p;
        nw0 = n0 & 1023;
    } else {
        WA = W0p;
        nw0 = n0;
    }

    auto stage = [&](int buf, int kt) {
        const ushort_t *Acur, *Wcur;
        if (MODE == 0) { Acur = Aa; Wcur = WA; }
        else {
            int pass = kt >> 4;
            Acur = (pass == 2) ? Ab : Aa;
            Wcur = (pass == 1) ? W1p : W0p;
        }
        const int k0 = (MODE ? (kt & 15) : kt) * 64;
        #pragma unroll
        for (int it = 0; it < 4; ++it) {       // A: 1024 16B-chunks
            int idx = (it * 4 + w) * 64 + lane;
            int row = idx >> 3, c8 = idx & 7;
            gl2lds16(&Acur[(size_t)(m0 + row) * E_ + k0 + ((c8 ^ (row & 7)) << 3)],
                     &As[buf][(it * 4 + w) * 512]);
        }
        #pragma unroll
        for (int it = 0; it < 2; ++it) {       // W: 512 16B-chunks
            int idx = (it * 4 + w) * 64 + lane;
            int row = idx >> 3, c8 = idx & 7;
            gl2lds16(&Wcur[(size_t)(nw0 + row) * E_ + k0 + ((c8 ^ (row & 7)) << 3)],
                     &Ws[buf][(it * 4 + w) * 512]);
        }
    };

    f32x4 acc[4][2];
    #pragma unroll
    for (int i = 0; i < 4; ++i)
        #pragma unroll
        for (int j = 0; j < 2; ++j) acc[i][j] = (f32x4){0.f, 0.f, 0.f, 0.f};

    stage(0, 0);
    __syncthreads();

    for (int kt = 0; kt < NT; ++kt) {
        const int cur = kt & 1;
        if (kt + 1 < NT) stage(cur ^ 1, kt + 1);
        #pragma unroll
        for (int h = 0; h < 2; ++h) {
            bf16x8 af[4], wf[2];
            #pragma unroll
            for (int i = 0; i < 4; ++i)
                af[i] = *(const bf16x8*)&As[cur][(wr * 64 + i * 16 + qi) * 64 +
                                                 (((h * 4 + g) ^ sw) << 3)];
            #pragma unroll
            for (int j = 0; j < 2; ++j)
                wf[j] = *(const bf16x8*)&Ws[cur][(wc * 32 + j * 16 + qi) * 64 +
                                                 (((h * 4 + g) ^ sw) << 3)];
            __builtin_amdgcn_s_setprio(1);
            #pragma unroll
            for (int i = 0; i < 4; ++i)
                #pragma unroll
                for (int j = 0; j < 2; ++j)
                    acc[i][j] = __builtin_amdgcn_mfma_f32_16x16x32_bf16(
                        af[i], wf[j], acc[i][j], 0, 0, 0);
            __builtin_amdgcn_s_setprio(0);
        }
        __syncthreads();   // drains vmcnt (next buf staged) + protects cur buf
    }

    if (MODE == 0) {
        ushort_t* Out = (region == 0) ? O0 : (region == 1) ? O1 : O2;
        const float oscale = (region == 0) ? 0.125f : 1.0f;
        const int hh = (n0 & 1023) >> 6;   // whole block in one head
        #pragma unroll
        for (int j = 0; j < 2; ++j) {
            const int n = n0 + wc * 32 + j * 16 + qi;
            const int d = n & 63;
            const float bj = bias[n];
            #pragma unroll
            for (int i = 0; i < 4; ++i)
                #pragma unroll
                for (int r = 0; r < 4; ++r) {
                    const int m = m0 + wr * 64 + i * 16 + g * 4 + r;
                    const int b = m >> 11, s = m & (S_ - 1);
                    Out[(((size_t)(b * H_ + hh)) * S_ + s) * HD_ + d] =
                        f2bf((acc[i][j][r] + bj) * oscale);
                }
        }
    } else {
        #pragma unroll
        for (int j = 0; j < 2; ++j) {
            const int n = n0 + wc * 32 + j * 16 + qi;
            const float bj = bias[n];
            #pragma unroll
            for (int i = 0; i < 4; ++i)
                #pragma unroll
                for (int r = 0; r < 4; ++r) {
                    const int m = m0 + wr * 64 + i * 16 + g * 4 + r;
                    Of[(size_t)m * E_ + n] = acc[i][j][r] + bj;
                }
        }
    }
}

// ---------------------------------------------------------------------------
// MFMA flash attention (verified R3 structure) + setprio around MFMA.
// ---------------------------------------------------------------------------
__global__ __launch_bounds__(256)
void attn_mfma(const ushort_t* __restrict__ Qg, const ushort_t* __restrict__ Kg,
               const ushort_t* __restrict__ Vg,
               ushort_t* __restrict__ Ohi, ushort_t* __restrict__ Olo)
{
    __shared__ ushort_t KsT[2][64][64];
    __shared__ ushort_t VtT[2][64][64];
    __shared__ ushort_t Qs[64][64];
    __shared__ ushort_t Ps[4][16][64];

    const int t    = threadIdx.x;
    const int w    = t >> 6;
    const int lane = t & 63;
    const int g    = lane >> 4;
    const int qi   = lane & 15;
    const int sw   = qi & 7;
    const int bh   = blockIdx.y;
    const int q0   = blockIdx.x * 64;
    const size_t base = (size_t)bh * S_ * HD_;

    #pragma unroll
    for (int it = 0; it < 2; ++it) {
        int idx = t + it * 256;
        int row = idx >> 3, c8 = idx & 7;
        uint4 qv = *(const uint4*)&Qg[base + (size_t)(q0 + row) * HD_ + c8 * 8];
        *(uint4*)&Qs[row][8 * (c8 ^ (row & 7))] = qv;
        uint4 kv = *(const uint4*)&Kg[base + (size_t)(row) * HD_ + c8 * 8];
        *(uint4*)&KsT[0][row][8 * (c8 ^ (row & 7))] = kv;
    }
    {
        const int kvg = t >> 4, dg = t & 15;
        u16x4 vv[4];
        #pragma unroll
        for (int j = 0; j < 4; ++j)
            vv[j] = *(const u16x4*)&Vg[base + (size_t)(kvg * 4 + j) * HD_ + dg * 4];
        #pragma unroll
        for (int i = 0; i < 4; ++i) {
            int d = dg * 4 + i;
            u16x4 wvec = { vv[0][i], vv[1][i], vv[2][i], vv[3][i] };
            *(u16x4*)&VtT[0][d][8 * ((kvg >> 1) ^ (d & 7)) + 4 * (kvg & 1)] = wvec;
        }
    }
    __syncthreads();

    const bf16x8 qf0 = *(const bf16x8*)&Qs[w * 16 + qi][8 * ((0 + g) ^ sw)];
    const bf16x8 qf1 = *(const bf16x8*)&Qs[w * 16 + qi][8 * ((4 + g) ^ sw)];

    float m_run = -3.0e38f, l_run = 0.f;
    f32x4 oacc[4];
    #pragma unroll
    for (int rb = 0; rb < 4; ++rb) oacc[rb] = (f32x4){0.f, 0.f, 0.f, 0.f};

    for (int tile = 0; tile < S_ / 64; ++tile) {
        const int cur = tile & 1;

        uint4 kpre[2];
        u16x4 vpre[4];
        const int kvg = t >> 4, dg = t & 15;
        if (tile < S_ / 64 - 1) {
            const size_t nb = base + (size_t)(tile + 1) * 64 * HD_;
            #pragma unroll
            for (int it = 0; it < 2; ++it) {
                int idx = t + it * 256;
                int row = idx >> 3, c8 = idx & 7;
                kpre[it] = *(const uint4*)&Kg[nb + (size_t)row * HD_ + c8 * 8];
            }
            #pragma unroll
            for (int j = 0; j < 4; ++j)
                vpre[j] = *(const u16x4*)&Vg[nb + (size_t)(kvg * 4 + j) * HD_ + dg * 4];
        }

        f32x4 sacc[4];
        __builtin_amdgcn_s_setprio(1);
        #pragma unroll
        for (int rb = 0; rb < 4; ++rb) {
            bf16x8 ka0 = *(const bf16x8*)&KsT[cur][rb * 16 + qi][8 * ((0 + g) ^ sw)];
            bf16x8 ka1 = *(const bf16x8*)&KsT[cur][rb * 16 + qi][8 * ((4 + g) ^ sw)];
            f32x4 z = (f32x4){0.f, 0.f, 0.f, 0.f};
            z = __builtin_amdgcn_mfma_f32_16x16x32_bf16(ka0, qf0, z, 0, 0, 0);
            z = __builtin_amdgcn_mfma_f32_16x16x32_bf16(ka1, qf1, z, 0, 0, 0);
            sacc[rb] = z;
        }
        __builtin_amdgcn_s_setprio(0);

        float smax = sacc[0][0];
        #pragma unroll
        for (int rb = 0; rb < 4; ++rb)
            #pragma unroll
            for (int r = 0; r < 4; ++r) smax = fmaxf(smax, sacc[rb][r]);
        smax = fmaxf(smax, __shfl_xor(smax, 16));
        smax = fmaxf(smax, __shfl_xor(smax, 32));
        const float mnew  = fmaxf(m_run, smax);
        const float alpha = __expf(m_run - mnew);
        float psum = 0.f;
        ushort_t pb[4][4];
        #pragma unroll
        for (int rb = 0; rb < 4; ++rb)
            #pragma unroll
            for (int r = 0; r < 4; ++r) {
                float p = __expf(sacc[rb][r] - mnew);
                psum += p;
                pb[rb][r] = f2bf(p);
            }
        psum += __shfl_xor(psum, 16);
        psum += __shfl_xor(psum, 32);
        l_run = l_run * alpha + psum;
        m_run = mnew;
        #pragma unroll
        for (int rb = 0; rb < 4; ++rb)
            #pragma unroll
            for (int r = 0; r < 4; ++r) oacc[rb][r] *= alpha;

        #pragma unroll
        for (int rb = 0; rb < 4; ++rb) {
            u16x4 pv = { pb[rb][0], pb[rb][1], pb[rb][2], pb[rb][3] };
            int ch = (2 * rb + (g >> 1)) ^ sw;
            *(u16x4*)&Ps[w][qi][8 * ch + 4 * (g & 1)] = pv;
        }

        __builtin_amdgcn_s_setprio(1);
        #pragma unroll
        for (int kc = 0; kc < 2; ++kc) {
            bf16x8 pf = *(const bf16x8*)&Ps[w][qi][8 * ((4 * kc + g) ^ sw)];
            #pragma unroll
            for (int rb = 0; rb < 4; ++rb) {
                bf16x8 va = *(const bf16x8*)&VtT[cur][rb * 16 + qi][8 * ((4 * kc + g) ^ sw)];
                oacc[rb] = __builtin_amdgcn_mfma_f32_16x16x32_bf16(va, pf, oacc[rb], 0, 0, 0);
            }
        }
        __builtin_amdgcn_s_setprio(0);

        __syncthreads();
        if (tile < S_ / 64 - 1) {
            #pragma unroll
            for (int it = 0; it < 2; ++it) {
                int idx = t + it * 256;
                int row = idx >> 3, c8 = idx & 7;
                *(uint4*)&KsT[cur ^ 1][row][8 * (c8 ^ (row & 7))] = kpre[it];
            }
            #pragma unroll
            for (int i = 0; i < 4; ++i) {
                int d = dg * 4 + i;
                u16x4 wvec = { vpre[0][i], vpre[1][i], vpre[2][i], vpre[3][i] };
                *(u16x4*)&VtT[cur ^ 1][d][8 * ((kvg >> 1) ^ (d & 7)) + 4 * (kvg & 1)] = wvec;
            }
            __syncthreads();
        }
    }

    const float inv = 1.f / l_run;
    const int b = bh >> 4, h = bh & 15;
    const size_t orow = (size_t)(b * S_ + q0 + w * 16 + qi) * E_ + h * HD_;
    #pragma unroll
    for (int rb = 0; rb < 4; ++rb) {
        u16x4 hv, lv;
        #pragma unroll
        for (int r = 0; r < 4; ++r) {
            float v = oacc[rb][r] * inv;
            ushort_t hb = f2bf(v);
            hv[r] = hb;
            lv[r] = f2bf(v - bf2f(hb));
        }
        *(u16x4*)&Ohi[orow + rb * 16 + g * 4] = hv;
        *(u16x4*)&Olo[orow + rb * 16 + g * 4] = lv;
    }
}

extern "C" void kernel_launch(void* const* d_in, const int* in_sizes, int n_in,
                              void* d_out, int out_size, void* d_ws, size_t ws_size,
                              hipStream_t stream) {
    const float* x  = (const float*)d_in[0];
    const float* Wq = (const float*)d_in[1];
    const float* bq = (const float*)d_in[2];
    const float* Wk = (const float*)d_in[3];
    const float* bk = (const float*)d_in[4];
    const float* Wv = (const float*)d_in[5];
    const float* bv = (const float*)d_in[6];
    const float* Wo = (const float*)d_in[7];
    const float* bo = (const float*)d_in[8];
    float* out = (float*)d_out;

    const size_t T4 = (size_t)B_ * S_ * E_;   // 4,194,304
    const size_t W1 = (size_t)E_ * E_;        // 1,048,576
    ushort_t* xb   = (ushort_t*)d_ws;
    ushort_t* Wqb  = xb   + T4;
    ushort_t* Wkb  = Wqb  + W1;
    ushort_t* Wvb  = Wkb  + W1;
    ushort_t* Wohi = Wvb  + W1;
    ushort_t* Wolo = Wohi + W1;
    ushort_t* qws  = Wolo + W1;
    ushort_t* kws  = qws  + T4;
    ushort_t* vws  = kws  + T4;
    ushort_t* aohi = vws  + T4;
    ushort_t* aolo = aohi + T4;
    float*    bcat = (float*)(aolo + T4);     // 3072 floats

    dim3 blk(256);
    conv_pack<<<2048, blk, 0, stream>>>(x, Wq, Wk, Wv, Wo, bq, bk, bv,
                                        xb, Wqb, Wkb, Wvb, Wohi, Wolo, bcat);

    // fused QKV: grid = 48 n-blocks * 32 m-blocks (1D, XCD-swizzled in-kernel)
    gemm_mfma<0><<<48 * 32, blk, 0, stream>>>(xb, nullptr, Wqb, Wkb, Wvb, bcat,
                                              qws, kws, vws, nullptr);

    dim3 ga(S_ / 64, B_ * H_);    // (32, 32)
    attn_mfma<<<ga, blk, 0, stream>>>(qws, kws, vws, aohi, aolo);

    // output projection, K'=3072 split passes
    gemm_mfma<1><<<16 * 32, blk, 0, stream>>>(aohi, aolo, Wohi, Wolo, nullptr, bo,
                                              nullptr, nullptr, nullptr, out);
}

// Round 6
// 262.216 us; speedup vs baseline: 8.7086x; 1.0709x over previous
//
#include <hip/hip_runtime.h>
#include <hip/hip_bf16.h>

#define B_ 2
#define S_ 2048
#define E_ 1024
#define H_ 16
#define HD_ 64
#define M_ (B_ * S_)   // 4096

typedef __attribute__((ext_vector_type(8))) short bf16x8;
typedef __attribute__((ext_vector_type(4))) float f32x4;
typedef __attribute__((ext_vector_type(4))) unsigned short u16x4;
typedef unsigned short ushort_t;

static __device__ __forceinline__ ushort_t f2bf(float f) {
    union { __hip_bfloat16 b; ushort_t u; } cv;
    cv.b = __float2bfloat16(f);
    return cv.u;
}
static __device__ __forceinline__ float bf2f(ushort_t u) {
    union { unsigned int i; float f; } cv;
    cv.i = ((unsigned int)u) << 16;
    return cv.f;
}
// async global->LDS, 16B per lane; LDS dest = wave-uniform base + lane*16
static __device__ __forceinline__ void gl2lds16(const ushort_t* g, ushort_t* l) {
    __builtin_amdgcn_global_load_lds(
        (const __attribute__((address_space(1))) unsigned int*)g,
        (__attribute__((address_space(3))) unsigned int*)l,
        16, 0, 0);
}

// ---------------------------------------------------------------------------
// Fused conversion: x,Wq,Wk,Wv -> bf16; Wo -> (hi,lo) bf16 split; bias concat.
// ---------------------------------------------------------------------------
__global__ __launch_bounds__(256)
void conv_pack(const float* __restrict__ x,  const float* __restrict__ Wq,
               const float* __restrict__ Wk, const float* __restrict__ Wv,
               const float* __restrict__ Wo, const float* __restrict__ bq,
               const float* __restrict__ bk, const float* __restrict__ bv,
               ushort_t* __restrict__ xb,  ushort_t* __restrict__ Wqb,
               ushort_t* __restrict__ Wkb, ushort_t* __restrict__ Wvb,
               ushort_t* __restrict__ Wohi, ushort_t* __restrict__ Wolo,
               float* __restrict__ bcat)
{
    const int NX = (B_ * S_ * E_) / 4;   // 1,048,576
    const int NW = (E_ * E_) / 4;        // 262,144
    const int total = NX + 4 * NW + 768;
    for (int u = blockIdx.x * blockDim.x + threadIdx.x; u < total;
         u += gridDim.x * blockDim.x) {
        if (u < NX) {
            float4 v = ((const float4*)x)[u];
            u16x4 o = { f2bf(v.x), f2bf(v.y), f2bf(v.z), f2bf(v.w) };
            ((u16x4*)xb)[u] = o;
        } else if (u < NX + 3 * NW) {
            int r = (u - NX) >> 18;          // NW = 2^18
            int i = (u - NX) & (NW - 1);
            const float* src = (r == 0) ? Wq : ((r == 1) ? Wk : Wv);
            ushort_t*    dst = (r == 0) ? Wqb : ((r == 1) ? Wkb : Wvb);
            float4 v = ((const float4*)src)[i];
            u16x4 o = { f2bf(v.x), f2bf(v.y), f2bf(v.z), f2bf(v.w) };
            ((u16x4*)dst)[i] = o;
        } else if (u < NX + 4 * NW) {
            int i = u - NX - 3 * NW;
            float4 v = ((const float4*)Wo)[i];
            u16x4 hv, lv;
            float vv[4] = { v.x, v.y, v.z, v.w };
            #pragma unroll
            for (int r = 0; r < 4; ++r) {
                ushort_t hb = f2bf(vv[r]);
                hv[r] = hb;
                lv[r] = f2bf(vv[r] - bf2f(hb));
            }
            ((u16x4*)Wohi)[i] = hv;
            ((u16x4*)Wolo)[i] = lv;
        } else {
            int i = u - NX - 4 * NW;         // 0..767
            int r = i >> 8, ii = i & 255;
            const float* src = (r == 0) ? bq : ((r == 1) ? bk : bv);
            ((float4*)bcat)[r * 256 + ii] = ((const float4*)src)[ii];
        }
    }
}

// ---------------------------------------------------------------------------
// Unified MFMA GEMM (unchanged from R5).
// ---------------------------------------------------------------------------
template<int MODE>
__global__ __launch_bounds__(256)
void gemm_mfma(const ushort_t* __restrict__ Aa, const ushort_t* __restrict__ Ab,
               const ushort_t* __restrict__ W0p, const ushort_t* __restrict__ W1p,
               const ushort_t* __restrict__ W2p, const float* __restrict__ bias,
               ushort_t* __restrict__ O0, ushort_t* __restrict__ O1,
               ushort_t* __restrict__ O2, float* __restrict__ Of)
{
    constexpr int NBX = MODE ? 16 : 48;
    constexpr int NT  = MODE ? 48 : 16;
    __shared__ ushort_t As[2][128 * 64];
    __shared__ ushort_t Ws[2][64 * 64];

    const int nwg = NBX * (M_ / 128);
    const int b0  = blockIdx.x;
    const int bid = (b0 & 7) * (nwg >> 3) + (b0 >> 3);
    const int bx = bid % NBX, by = bid / NBX;
    const int m0 = by * 128, n0 = bx * 64;

    const int t = threadIdx.x;
    const int w = t >> 6, lane = t & 63;
    const int g = lane >> 4, qi = lane & 15, sw = qi & 7;
    const int wr = w >> 1, wc = w & 1;

    const ushort_t* WA;
    int nw0;
    int region = 0;
    if (MODE == 0) {
        region = n0 >> 10;
        WA = (region == 0) ? W0p : (region == 1) ? W1p : W2p;
        nw0 = n0 & 1023;
    } else {
        WA = W0p;
        nw0 = n0;
    }

    auto stage = [&](int buf, int kt) {
        const ushort_t *Acur, *Wcur;
        if (MODE == 0) { Acur = Aa; Wcur = WA; }
        else {
            int pass = kt >> 4;
            Acur = (pass == 2) ? Ab : Aa;
            Wcur = (pass == 1) ? W1p : W0p;
        }
        const int k0 = (MODE ? (kt & 15) : kt) * 64;
        #pragma unroll
        for (int it = 0; it < 4; ++it) {       // A: 1024 16B-chunks
            int idx = (it * 4 + w) * 64 + lane;
            int row = idx >> 3, c8 = idx & 7;
            gl2lds16(&Acur[(size_t)(m0 + row) * E_ + k0 + ((c8 ^ (row & 7)) << 3)],
                     &As[buf][(it * 4 + w) * 512]);
        }
        #pragma unroll
        for (int it = 0; it < 2; ++it) {       // W: 512 16B-chunks
            int idx = (it * 4 + w) * 64 + lane;
            int row = idx >> 3, c8 = idx & 7;
            gl2lds16(&Wcur[(size_t)(nw0 + row) * E_ + k0 + ((c8 ^ (row & 7)) << 3)],
                     &Ws[buf][(it * 4 + w) * 512]);
        }
    };

    f32x4 acc[4][2];
    #pragma unroll
    for (int i = 0; i < 4; ++i)
        #pragma unroll
        for (int j = 0; j < 2; ++j) acc[i][j] = (f32x4){0.f, 0.f, 0.f, 0.f};

    stage(0, 0);
    __syncthreads();

    for (int kt = 0; kt < NT; ++kt) {
        const int cur = kt & 1;
        if (kt + 1 < NT) stage(cur ^ 1, kt + 1);
        #pragma unroll
        for (int h = 0; h < 2; ++h) {
            bf16x8 af[4], wf[2];
            #pragma unroll
            for (int i = 0; i < 4; ++i)
                af[i] = *(const bf16x8*)&As[cur][(wr * 64 + i * 16 + qi) * 64 +
                                                 (((h * 4 + g) ^ sw) << 3)];
            #pragma unroll
            for (int j = 0; j < 2; ++j)
                wf[j] = *(const bf16x8*)&Ws[cur][(wc * 32 + j * 16 + qi) * 64 +
                                                 (((h * 4 + g) ^ sw) << 3)];
            __builtin_amdgcn_s_setprio(1);
            #pragma unroll
            for (int i = 0; i < 4; ++i)
                #pragma unroll
                for (int j = 0; j < 2; ++j)
                    acc[i][j] = __builtin_amdgcn_mfma_f32_16x16x32_bf16(
                        af[i], wf[j], acc[i][j], 0, 0, 0);
            __builtin_amdgcn_s_setprio(0);
        }
        __syncthreads();
    }

    if (MODE == 0) {
        ushort_t* Out = (region == 0) ? O0 : (region == 1) ? O1 : O2;
        const float oscale = (region == 0) ? 0.18033688f : 1.0f;  // q: 1/8 * log2(e)
        const int hh = (n0 & 1023) >> 6;
        #pragma unroll
        for (int j = 0; j < 2; ++j) {
            const int n = n0 + wc * 32 + j * 16 + qi;
            const int d = n & 63;
            const float bj = bias[n];
            #pragma unroll
            for (int i = 0; i < 4; ++i)
                #pragma unroll
                for (int r = 0; r < 4; ++r) {
                    const int m = m0 + wr * 64 + i * 16 + g * 4 + r;
                    const int b = m >> 11, s = m & (S_ - 1);
                    Out[(((size_t)(b * H_ + hh)) * S_ + s) * HD_ + d] =
                        f2bf((acc[i][j][r] + bj) * oscale);
                }
        }
    } else {
        #pragma unroll
        for (int j = 0; j < 2; ++j) {
            const int n = n0 + wc * 32 + j * 16 + qi;
            const float bj = bias[n];
            #pragma unroll
            for (int i = 0; i < 4; ++i)
                #pragma unroll
                for (int r = 0; r < 4; ++r) {
                    const int m = m0 + wr * 64 + i * 16 + g * 4 + r;
                    Of[(size_t)m * E_ + n] = acc[i][j][r] + bj;
                }
        }
    }
}

// ---------------------------------------------------------------------------
// MFMA flash attention v2: 128 q-rows/block, 32 q-rows/wave (2 q-column
// blocks of 16), kv-tiles of 64 double-buffered. Q fragments from global
// (no Q LDS). K staged via global_load_lds w/ pre-swizzled source. V staged
// transposed via register transpose. Softmax in exp2 domain (Q pre-scaled
// by 0.125*log2e). K/V fragment reads shared across the 2 q-blocks ->
// half the LDS traffic per FLOP vs v1. One barrier per tile.
// ---------------------------------------------------------------------------
__global__ __launch_bounds__(256)
void attn_mfma(const ushort_t* __restrict__ Qg, const ushort_t* __restrict__ Kg,
               const ushort_t* __restrict__ Vg,
               ushort_t* __restrict__ Ohi, ushort_t* __restrict__ Olo)
{
    __shared__ ushort_t Ks[2][64][64];    // K tile [kv][d], XOR-chunk swizzled
    __shared__ ushort_t VtT[2][64][64];   // V^T tile [d][kv], swizzled
    __shared__ ushort_t Ps[4][32][64];    // per-wave P [q][kv], swizzled

    const int t    = threadIdx.x;
    const int w    = t >> 6;
    const int lane = t & 63;
    const int g    = lane >> 4;
    const int qi   = lane & 15;
    const int sw   = qi & 7;
    const int bh   = blockIdx.y;
    const int q0   = blockIdx.x * 128;
    const size_t base = (size_t)bh * S_ * HD_;
    const int kvg = t >> 4, dg = t & 15;   // V staging roles

    auto stageK = [&](int buf, int tile) {
        const size_t nb = base + (size_t)tile * 64 * HD_;
        #pragma unroll
        for (int it = 0; it < 2; ++it) {
            int u = w * 128 + it * 64 + lane;
            int row = u >> 3, c8 = u & 7;
            gl2lds16(&Kg[nb + (size_t)row * HD_ + ((c8 ^ (row & 7)) << 3)],
                     &Ks[buf][0][0] + (size_t)(w * 128 + it * 64) * 8);
        }
    };

    // Q fragments straight from global (once per block)
    bf16x8 qf[2][2];
    #pragma unroll
    for (int qc = 0; qc < 2; ++qc)
        #pragma unroll
        for (int h = 0; h < 2; ++h)
            qf[qc][h] = *(const bf16x8*)&Qg[base +
                (size_t)(q0 + w * 32 + qc * 16 + qi) * HD_ + (h * 4 + g) * 8];

    // prologue: stage tile 0
    stageK(0, 0);
    {
        u16x4 vv[4];
        #pragma unroll
        for (int j = 0; j < 4; ++j)
            vv[j] = *(const u16x4*)&Vg[base + (size_t)(kvg * 4 + j) * HD_ + dg * 4];
        #pragma unroll
        for (int i = 0; i < 4; ++i) {
            int d = dg * 4 + i;
            u16x4 wvec = { vv[0][i], vv[1][i], vv[2][i], vv[3][i] };
            *(u16x4*)&VtT[0][d][8 * ((kvg >> 1) ^ (d & 7)) + 4 * (kvg & 1)] = wvec;
        }
    }
    __syncthreads();

    float m_run[2] = { -3.0e38f, -3.0e38f };
    float l_run[2] = { 0.f, 0.f };
    f32x4 oacc[2][4];
    #pragma unroll
    for (int qc = 0; qc < 2; ++qc)
        #pragma unroll
        for (int rb = 0; rb < 4; ++rb) oacc[qc][rb] = (f32x4){0.f, 0.f, 0.f, 0.f};

    for (int tile = 0; tile < S_ / 64; ++tile) {
        const int cur = tile & 1;
        const bool has_next = (tile + 1 < S_ / 64);

        u16x4 vpre[4];
        if (has_next) {
            stageK(cur ^ 1, tile + 1);
            const size_t nb = base + (size_t)(tile + 1) * 64 * HD_;
            #pragma unroll
            for (int j = 0; j < 4; ++j)
                vpre[j] = *(const u16x4*)&Vg[nb + (size_t)(kvg * 4 + j) * HD_ + dg * 4];
        }

        // ---- QK^T -> S^T for both q-blocks; K frags shared
        f32x4 sacc[2][4];
        #pragma unroll
        for (int rb = 0; rb < 4; ++rb) {
            bf16x8 ka0 = *(const bf16x8*)&Ks[cur][rb * 16 + qi][8 * ((0 + g) ^ sw)];
            bf16x8 ka1 = *(const bf16x8*)&Ks[cur][rb * 16 + qi][8 * ((4 + g) ^ sw)];
            #pragma unroll
            for (int qc = 0; qc < 2; ++qc) {
                f32x4 z = (f32x4){0.f, 0.f, 0.f, 0.f};
                z = __builtin_amdgcn_mfma_f32_16x16x32_bf16(ka0, qf[qc][0], z, 0, 0, 0);
                z = __builtin_amdgcn_mfma_f32_16x16x32_bf16(ka1, qf[qc][1], z, 0, 0, 0);
                sacc[qc][rb] = z;
            }
        }

        // ---- online softmax (exp2 domain) + P write, per q-block
        #pragma unroll
        for (int qc = 0; qc < 2; ++qc) {
            float smax = sacc[qc][0][0];
            #pragma unroll
            for (int rb = 0; rb < 4; ++rb)
                #pragma unroll
                for (int r = 0; r < 4; ++r) smax = fmaxf(smax, sacc[qc][rb][r]);
            smax = fmaxf(smax, __shfl_xor(smax, 16));
            smax = fmaxf(smax, __shfl_xor(smax, 32));
            const float mnew  = fmaxf(m_run[qc], smax);
            const float alpha = exp2f(m_run[qc] - mnew);
            float psum = 0.f;
            #pragma unroll
            for (int rb = 0; rb < 4; ++rb) {
                u16x4 pv;
                #pragma unroll
                for (int r = 0; r < 4; ++r) {
                    float p = exp2f(sacc[qc][rb][r] - mnew);
                    psum += p;
                    pv[r] = f2bf(p);
                }
                int ch = (2 * rb + (g >> 1)) ^ sw;
                *(u16x4*)&Ps[w][qc * 16 + qi][8 * ch + 4 * (g & 1)] = pv;
            }
            psum += __shfl_xor(psum, 16);
            psum += __shfl_xor(psum, 32);
            l_run[qc] = l_run[qc] * alpha + psum;
            m_run[qc] = mnew;
            #pragma unroll
            for (int rb = 0; rb < 4; ++rb)
                #pragma unroll
                for (int r = 0; r < 4; ++r) oacc[qc][rb][r] *= alpha;
        }

        // ---- PV: O^T += V^T P^T ; V frags shared across q-blocks
        #pragma unroll
        for (int kc = 0; kc < 2; ++kc) {
            bf16x8 pf0 = *(const bf16x8*)&Ps[w][qi][8 * ((4 * kc + g) ^ sw)];
            bf16x8 pf1 = *(const bf16x8*)&Ps[w][16 + qi][8 * ((4 * kc + g) ^ sw)];
            #pragma unroll
            for (int rb = 0; rb < 4; ++rb) {
                bf16x8 va = *(const bf16x8*)&VtT[cur][rb * 16 + qi][8 * ((4 * kc + g) ^ sw)];
                oacc[0][rb] = __builtin_amdgcn_mfma_f32_16x16x32_bf16(va, pf0, oacc[0][rb], 0, 0, 0);
                oacc[1][rb] = __builtin_amdgcn_mfma_f32_16x16x32_bf16(va, pf1, oacc[1][rb], 0, 0, 0);
            }
        }

        // ---- write next V^T, then the single barrier
        if (has_next) {
            #pragma unroll
            for (int i = 0; i < 4; ++i) {
                int d = dg * 4 + i;
                u16x4 wvec = { vpre[0][i], vpre[1][i], vpre[2][i], vpre[3][i] };
                *(u16x4*)&VtT[cur ^ 1][d][8 * ((kvg >> 1) ^ (d & 7)) + 4 * (kvg & 1)] = wvec;
            }
        }
        __syncthreads();
    }

    // ---- epilogue: normalize, split hi/lo, write [B,S,E]
    const int b = bh >> 4, h = bh & 15;
    #pragma unroll
    for (int qc = 0; qc < 2; ++qc) {
        const float inv = 1.f / l_run[qc];
        const size_t orow =
            (size_t)(b * S_ + q0 + w * 32 + qc * 16 + qi) * E_ + h * HD_;
        #pragma unroll
        for (int rb = 0; rb < 4; ++rb) {
            u16x4 hv, lv;
            #pragma unroll
            for (int r = 0; r < 4; ++r) {
                float v = oacc[qc][rb][r] * inv;
                ushort_t hb = f2bf(v);
                hv[r] = hb;
                lv[r] = f2bf(v - bf2f(hb));
            }
            *(u16x4*)&Ohi[orow + rb * 16 + g * 4] = hv;
            *(u16x4*)&Olo[orow + rb * 16 + g * 4] = lv;
        }
    }
}

extern "C" void kernel_launch(void* const* d_in, const int* in_sizes, int n_in,
                              void* d_out, int out_size, void* d_ws, size_t ws_size,
                              hipStream_t stream) {
    const float* x  = (const float*)d_in[0];
    const float* Wq = (const float*)d_in[1];
    const float* bq = (const float*)d_in[2];
    const float* Wk = (const float*)d_in[3];
    const float* bk = (const float*)d_in[4];
    const float* Wv = (const float*)d_in[5];
    const float* bv = (const float*)d_in[6];
    const float* Wo = (const float*)d_in[7];
    const float* bo = (const float*)d_in[8];
    float* out = (float*)d_out;

    const size_t T4 = (size_t)B_ * S_ * E_;   // 4,194,304
    const size_t W1 = (size_t)E_ * E_;        // 1,048,576
    ushort_t* xb   = (ushort_t*)d_ws;
    ushort_t* Wqb  = xb   + T4;
    ushort_t* Wkb  = Wqb  + W1;
    ushort_t* Wvb  = Wkb  + W1;
    ushort_t* Wohi = Wvb  + W1;
    ushort_t* Wolo = Wohi + W1;
    ushort_t* qws  = Wolo + W1;
    ushort_t* kws  = qws  + T4;
    ushort_t* vws  = kws  + T4;
    ushort_t* aohi = vws  + T4;
    ushort_t* aolo = aohi + T4;
    float*    bcat = (float*)(aolo + T4);     // 3072 floats

    dim3 blk(256);
    conv_pack<<<2048, blk, 0, stream>>>(x, Wq, Wk, Wv, Wo, bq, bk, bv,
                                        xb, Wqb, Wkb, Wvb, Wohi, Wolo, bcat);

    gemm_mfma<0><<<48 * 32, blk, 0, stream>>>(xb, nullptr, Wqb, Wkb, Wvb, bcat,
                                              qws, kws, vws, nullptr);

    dim3 ga(S_ / 128, B_ * H_);   // (16, 32)
    attn_mfma<<<ga, blk, 0, stream>>>(qws, kws, vws, aohi, aolo);

    gemm_mfma<1><<<16 * 32, blk, 0, stream>>>(aohi, aolo, Wohi, Wolo, nullptr, bo,
                                              nullptr, nullptr, nullptr, out);
}

// Round 7
// 238.091 us; speedup vs baseline: 9.5909x; 1.1013x over previous
//
#include <hip/hip_runtime.h>

#define B_ 2
#define S_ 2048
#define E_ 1024
#define H_ 16
#define HD_ 64
#define M_ (B_ * S_)      // 4096
#define BH_ (B_ * H_)     // 32
#define NROWS (BH_ * S_)  // 65536

typedef __attribute__((ext_vector_type(8))) _Float16 half8;
typedef __attribute__((ext_vector_type(4))) float f32x4;
typedef __attribute__((ext_vector_type(4))) unsigned short u16x4;
typedef __attribute__((ext_vector_type(8))) unsigned short u16x8;
typedef unsigned short ushort_t;

static __device__ __forceinline__ ushort_t f2h(float f) {
    union { _Float16 h; ushort_t u; } c; c.h = (_Float16)f; return c.u;
}
static __device__ __forceinline__ float h2f(ushort_t u) {
    union { _Float16 h; ushort_t u; } c; c.u = u; return (float)c.h;
}
// async global->LDS, 16B/lane; LDS dest = wave-uniform base + lane*16
static __device__ __forceinline__ void gl2lds16(const ushort_t* g, ushort_t* l) {
    __builtin_amdgcn_global_load_lds(
        (const __attribute__((address_space(1))) unsigned int*)g,
        (__attribute__((address_space(3))) unsigned int*)l,
        16, 0, 0);
}

// ---------------------------------------------------------------------------
// Conversion: x, Wq, Wk, Wv, Wo -> fp16; QKV bias concat (fp32).
// ---------------------------------------------------------------------------
__global__ __launch_bounds__(256)
void conv_pack(const float* __restrict__ x,  const float* __restrict__ Wq,
               const float* __restrict__ Wk, const float* __restrict__ Wv,
               const float* __restrict__ Wo, const float* __restrict__ bq,
               const float* __restrict__ bk, const float* __restrict__ bv,
               ushort_t* __restrict__ xh,  ushort_t* __restrict__ Wqh,
               ushort_t* __restrict__ Wkh, ushort_t* __restrict__ Wvh,
               ushort_t* __restrict__ Woh, float* __restrict__ bcat)
{
    const int NX = (B_ * S_ * E_) / 4;   // 1,048,576 float4 units
    const int NW = (E_ * E_) / 4;        // 262,144
    const int total = NX + 4 * NW + 768;
    for (int u = blockIdx.x * blockDim.x + threadIdx.x; u < total;
         u += gridDim.x * blockDim.x) {
        if (u < NX) {
            float4 v = ((const float4*)x)[u];
            u16x4 o = { f2h(v.x), f2h(v.y), f2h(v.z), f2h(v.w) };
            ((u16x4*)xh)[u] = o;
        } else if (u < NX + 4 * NW) {
            int r = (u - NX) >> 18;          // NW = 2^18
            int i = (u - NX) & (NW - 1);
            const float* src = (r == 0) ? Wq : (r == 1) ? Wk : (r == 2) ? Wv : Wo;
            ushort_t*    dst = (r == 0) ? Wqh : (r == 1) ? Wkh : (r == 2) ? Wvh : Woh;
            float4 v = ((const float4*)src)[i];
            u16x4 o = { f2h(v.x), f2h(v.y), f2h(v.z), f2h(v.w) };
            ((u16x4*)dst)[i] = o;
        } else {
            int i = u - NX - 4 * NW;         // 0..767
            int r = i >> 8, ii = i & 255;
            const float* src = (r == 0) ? bq : (r == 1) ? bk : bv;
            ((float4*)bcat)[r * 256 + ii] = ((const float4*)src)[ii];
        }
    }
}

// ---------------------------------------------------------------------------
// Fused QKV GEMM, fp16 MFMA. m97-structure: 128x128 tile, BK=64, single
// 32KB LDS buffer, 2 barriers/K-step, glds(16B) staging with pre-swizzled
// source (XOR c8^(row&7) involution). Grid 768 = 3 blocks/CU (LDS allows 5).
// N=3072 in 3 regions (Wq/Wk/Wv); bf16->fp16 out scattered to [B,H,S,HD];
// q region scaled by 0.125*log2(e) (exp2-domain softmax downstream).
// ---------------------------------------------------------------------------
__global__ __launch_bounds__(256)
void gemm_qkv(const ushort_t* __restrict__ Ah, const ushort_t* __restrict__ W0p,
              const ushort_t* __restrict__ W1p, const ushort_t* __restrict__ W2p,
              const float* __restrict__ bias,
              ushort_t* __restrict__ O0, ushort_t* __restrict__ O1,
              ushort_t* __restrict__ O2)
{
    __shared__ ushort_t As[128 * 64];
    __shared__ ushort_t Ws[128 * 64];

    const int nwg = 24 * 32;   // 768, %8 == 0 -> simple bijective XCD swizzle
    const int b0  = blockIdx.x;
    const int bid = (b0 & 7) * (nwg >> 3) + (b0 >> 3);
    const int bx = bid % 24, by = bid / 24;
    const int m0 = by * 128, n0 = bx * 128;

    const int t = threadIdx.x;
    const int w = t >> 6, lane = t & 63;
    const int g = lane >> 4, qi = lane & 15, sw = qi & 7;
    const int wr = w >> 1, wc = w & 1;

    const int region = n0 >> 10;           // tile never straddles (128 | 1024)
    const ushort_t* WA = (region == 0) ? W0p : (region == 1) ? W1p : W2p;
    const int nw0 = n0 & 1023;

    f32x4 acc[4][4];
    #pragma unroll
    for (int i = 0; i < 4; ++i)
        #pragma unroll
        for (int j = 0; j < 4; ++j) acc[i][j] = (f32x4){0.f, 0.f, 0.f, 0.f};

    for (int kt = 0; kt < 16; ++kt) {
        __syncthreads();                   // readers of previous tile done
        const int k0 = kt * 64;
        #pragma unroll
        for (int it = 0; it < 4; ++it) {   // A: 1024 16B chunks
            int idx = (it * 4 + w) * 64 + lane;
            int row = idx >> 3, c8 = idx & 7;
            gl2lds16(&Ah[(size_t)(m0 + row) * E_ + k0 + ((c8 ^ (row & 7)) << 3)],
                     &As[(it * 4 + w) * 512]);
        }
        #pragma unroll
        for (int it = 0; it < 4; ++it) {   // W: 1024 16B chunks
            int idx = (it * 4 + w) * 64 + lane;
            int row = idx >> 3, c8 = idx & 7;
            gl2lds16(&WA[(size_t)(nw0 + row) * E_ + k0 + ((c8 ^ (row & 7)) << 3)],
                     &Ws[(it * 4 + w) * 512]);
        }
        __syncthreads();                   // vmcnt drained by compiler here

        #pragma unroll
        for (int h = 0; h < 2; ++h) {
            half8 af[4], wf[4];
            #pragma unroll
            for (int i = 0; i < 4; ++i)
                af[i] = *(const half8*)&As[(wr * 64 + i * 16 + qi) * 64 +
                                           (((h * 4 + g) ^ sw) << 3)];
            #pragma unroll
            for (int j = 0; j < 4; ++j)
                wf[j] = *(const half8*)&Ws[(wc * 64 + j * 16 + qi) * 64 +
                                           (((h * 4 + g) ^ sw) << 3)];
            __builtin_amdgcn_s_setprio(1);
            #pragma unroll
            for (int i = 0; i < 4; ++i)
                #pragma unroll
                for (int j = 0; j < 4; ++j)
                    acc[i][j] = __builtin_amdgcn_mfma_f32_16x16x32_f16(
                        af[i], wf[j], acc[i][j], 0, 0, 0);
            __builtin_amdgcn_s_setprio(0);
        }
    }

    ushort_t* Out = (region == 0) ? O0 : (region == 1) ? O1 : O2;
    const float osc = (region == 0) ? 0.18033688f : 1.0f;  // 1/8 * log2(e)
    #pragma unroll
    for (int j = 0; j < 4; ++j) {
        const int n = n0 + wc * 64 + j * 16 + qi;
        const int nn = n & 1023;
        const int hh = nn >> 6, d = nn & 63;
        const float bj = bias[n];
        #pragma unroll
        for (int i = 0; i < 4; ++i)
            #pragma unroll
            for (int r = 0; r < 4; ++r) {
                const int m = m0 + wr * 64 + i * 16 + g * 4 + r;
                const int b = m >> 11, s = m & (S_ - 1);
                Out[(((size_t)(b * H_ + hh)) * S_ + s) * HD_ + d] =
                    f2h((acc[i][j][r] + bj) * osc);
            }
    }
}

// ---------------------------------------------------------------------------
// Output projection GEMM, fp16 single-pass (fp16 rel err 2^-11 -> dot error
// ~7e-5 std, far under threshold). 128x64 tile, double-buffered (R6-proven
// structure), fp32 output + bias.
// ---------------------------------------------------------------------------
__global__ __launch_bounds__(256)
void gemm_out(const ushort_t* __restrict__ Ah, const ushort_t* __restrict__ Wh,
              const float* __restrict__ bo, float* __restrict__ Of)
{
    __shared__ ushort_t As[2][128 * 64];
    __shared__ ushort_t Ws[2][64 * 64];

    const int nwg = 16 * 32;   // 512
    const int b0  = blockIdx.x;
    const int bid = (b0 & 7) * (nwg >> 3) + (b0 >> 3);
    const int bx = bid % 16, by = bid / 16;
    const int m0 = by * 128, n0 = bx * 64;

    const int t = threadIdx.x;
    const int w = t >> 6, lane = t & 63;
    const int g = lane >> 4, qi = lane & 15, sw = qi & 7;
    const int wr = w >> 1, wc = w & 1;

    auto stage = [&](int buf, int kt) {
        const int k0 = kt * 64;
        #pragma unroll
        for (int it = 0; it < 4; ++it) {
            int idx = (it * 4 + w) * 64 + lane;
            int row = idx >> 3, c8 = idx & 7;
            gl2lds16(&Ah[(size_t)(m0 + row) * E_ + k0 + ((c8 ^ (row & 7)) << 3)],
                     &As[buf][(it * 4 + w) * 512]);
        }
        #pragma unroll
        for (int it = 0; it < 2; ++it) {
            int idx = (it * 4 + w) * 64 + lane;
            int row = idx >> 3, c8 = idx & 7;
            gl2lds16(&Wh[(size_t)(n0 + row) * E_ + k0 + ((c8 ^ (row & 7)) << 3)],
                     &Ws[buf][(it * 4 + w) * 512]);
        }
    };

    f32x4 acc[4][2];
    #pragma unroll
    for (int i = 0; i < 4; ++i)
        #pragma unroll
        for (int j = 0; j < 2; ++j) acc[i][j] = (f32x4){0.f, 0.f, 0.f, 0.f};

    stage(0, 0);
    __syncthreads();

    for (int kt = 0; kt < 16; ++kt) {
        const int cur = kt & 1;
        if (kt + 1 < 16) stage(cur ^ 1, kt + 1);
        #pragma unroll
        for (int h = 0; h < 2; ++h) {
            half8 af[4], wf[2];
            #pragma unroll
            for (int i = 0; i < 4; ++i)
                af[i] = *(const half8*)&As[cur][(wr * 64 + i * 16 + qi) * 64 +
                                                (((h * 4 + g) ^ sw) << 3)];
            #pragma unroll
            for (int j = 0; j < 2; ++j)
                wf[j] = *(const half8*)&Ws[cur][(wc * 32 + j * 16 + qi) * 64 +
                                                (((h * 4 + g) ^ sw) << 3)];
            __builtin_amdgcn_s_setprio(1);
            #pragma unroll
            for (int i = 0; i < 4; ++i)
                #pragma unroll
                for (int j = 0; j < 2; ++j)
                    acc[i][j] = __builtin_amdgcn_mfma_f32_16x16x32_f16(
                        af[i], wf[j], acc[i][j], 0, 0, 0);
            __builtin_amdgcn_s_setprio(0);
        }
        __syncthreads();
    }

    #pragma unroll
    for (int j = 0; j < 2; ++j) {
        const int n = n0 + wc * 32 + j * 16 + qi;
        const float bj = bo[n];
        #pragma unroll
        for (int i = 0; i < 4; ++i)
            #pragma unroll
            for (int r = 0; r < 4; ++r) {
                const int m = m0 + wr * 64 + i * 16 + g * 4 + r;
                Of[(size_t)m * E_ + n] = acc[i][j][r] + bj;
            }
    }
}

// ---------------------------------------------------------------------------
// MFMA flash attention v3, fp16, KV-SPLIT x2 (blockIdx.z = kv half).
// 128 q-rows/block, 32/wave (2 q-col blocks). Each split handles 16 kv-tiles
// and emits normalized O (fp16) + per-row (m,l); combine kernel merges.
// Defer-max (T13, THR=8 in exp2 domain): skip O-rescale unless some row's
// tile max exceeds running max by >8 (P then bounded by 2^8, fp16-safe).
// Grid 1024 = 3 blocks/CU (48KB LDS) -> 12 waves/CU (was 8).
// ---------------------------------------------------------------------------
__global__ __launch_bounds__(256)
void attn_mfma(const ushort_t* __restrict__ Qg, const ushort_t* __restrict__ Kg,
               const ushort_t* __restrict__ Vg,
               ushort_t* __restrict__ On, float2* __restrict__ ml)
{
    __shared__ ushort_t Ks[2][64][64];    // K tile [kv][d], XOR-chunk swizzled
    __shared__ ushort_t VtT[2][64][64];   // V^T tile [d][kv], swizzled
    __shared__ ushort_t Ps[4][32][64];    // per-wave P [q][kv], swizzled

    const int t    = threadIdx.x;
    const int w    = t >> 6;
    const int lane = t & 63;
    const int g    = lane >> 4;
    const int qi   = lane & 15;
    const int sw   = qi & 7;
    const int bh   = blockIdx.y;
    const int q0   = blockIdx.x * 128;
    const int z    = blockIdx.z;          // kv half
    const int t0   = z * 16, t1 = t0 + 16;
    const size_t base = (size_t)bh * S_ * HD_;
    const int kvg = t >> 4, dg = t & 15;  // V staging roles

    auto stageK = [&](int buf, int tile) {
        const size_t nb = base + (size_t)tile * 64 * HD_;
        #pragma unroll
        for (int it = 0; it < 2; ++it) {
            int u = w * 128 + it * 64 + lane;
            int row = u >> 3, c8 = u & 7;
            gl2lds16(&Kg[nb + (size_t)row * HD_ + ((c8 ^ (row & 7)) << 3)],
                     &Ks[buf][0][0] + (size_t)(w * 128 + it * 64) * 8);
        }
    };

    // Q fragments straight from global (once per block)
    half8 qf[2][2];
    #pragma unroll
    for (int qc = 0; qc < 2; ++qc)
        #pragma unroll
        for (int h = 0; h < 2; ++h)
            qf[qc][h] = *(const half8*)&Qg[base +
                (size_t)(q0 + w * 32 + qc * 16 + qi) * HD_ + (h * 4 + g) * 8];

    // prologue: stage first tile of this split
    stageK(0, t0);
    {
        const size_t nb = base + (size_t)t0 * 64 * HD_;
        u16x4 vv[4];
        #pragma unroll
        for (int j = 0; j < 4; ++j)
            vv[j] = *(const u16x4*)&Vg[nb + (size_t)(kvg * 4 + j) * HD_ + dg * 4];
        #pragma unroll
        for (int i = 0; i < 4; ++i) {
            int d = dg * 4 + i;
            u16x4 wvec = { vv[0][i], vv[1][i], vv[2][i], vv[3][i] };
            *(u16x4*)&VtT[0][d][8 * ((kvg >> 1) ^ (d & 7)) + 4 * (kvg & 1)] = wvec;
        }
    }
    __syncthreads();

    float m_run[2] = { -3.0e38f, -3.0e38f };
    float l_run[2] = { 0.f, 0.f };
    f32x4 oacc[2][4];
    #pragma unroll
    for (int qc = 0; qc < 2; ++qc)
        #pragma unroll
        for (int rb = 0; rb < 4; ++rb) oacc[qc][rb] = (f32x4){0.f, 0.f, 0.f, 0.f};

    for (int tile = t0; tile < t1; ++tile) {
        const int cur = tile & 1;
        const bool has_next = (tile + 1 < t1);

        u16x4 vpre[4];
        if (has_next) {
            stageK(cur ^ 1, tile + 1);
            const size_t nb = base + (size_t)(tile + 1) * 64 * HD_;
            #pragma unroll
            for (int j = 0; j < 4; ++j)
                vpre[j] = *(const u16x4*)&Vg[nb + (size_t)(kvg * 4 + j) * HD_ + dg * 4];
        }

        // ---- QK^T -> S^T for both q-blocks; K frags shared
        f32x4 sacc[2][4];
        #pragma unroll
        for (int rb = 0; rb < 4; ++rb) {
            half8 ka0 = *(const half8*)&Ks[cur][rb * 16 + qi][8 * ((0 + g) ^ sw)];
            half8 ka1 = *(const half8*)&Ks[cur][rb * 16 + qi][8 * ((4 + g) ^ sw)];
            #pragma unroll
            for (int qc = 0; qc < 2; ++qc) {
                f32x4 zz = (f32x4){0.f, 0.f, 0.f, 0.f};
                zz = __builtin_amdgcn_mfma_f32_16x16x32_f16(ka0, qf[qc][0], zz, 0, 0, 0);
                zz = __builtin_amdgcn_mfma_f32_16x16x32_f16(ka1, qf[qc][1], zz, 0, 0, 0);
                sacc[qc][rb] = zz;
            }
        }

        // ---- online softmax (exp2 domain, defer-max) + P write
        #pragma unroll
        for (int qc = 0; qc < 2; ++qc) {
            float smax = sacc[qc][0][0];
            #pragma unroll
            for (int rb = 0; rb < 4; ++rb)
                #pragma unroll
                for (int r = 0; r < 4; ++r) smax = fmaxf(smax, sacc[qc][rb][r]);
            smax = fmaxf(smax, __shfl_xor(smax, 16));
            smax = fmaxf(smax, __shfl_xor(smax, 32));
            // defer-max: only rescale when some row exceeds running max by >8
            if (__any(smax > m_run[qc] + 8.0f)) {
                const float mnew  = fmaxf(m_run[qc], smax);
                const float alpha = exp2f(m_run[qc] - mnew);
                l_run[qc] *= alpha;
                #pragma unroll
                for (int rb = 0; rb < 4; ++rb)
                    #pragma unroll
                    for (int r = 0; r < 4; ++r) oacc[qc][rb][r] *= alpha;
                m_run[qc] = mnew;
            }
            float psum = 0.f;
            #pragma unroll
            for (int rb = 0; rb < 4; ++rb) {
                u16x4 pv;
                #pragma unroll
                for (int r = 0; r < 4; ++r) {
                    float p = exp2f(sacc[qc][rb][r] - m_run[qc]);
                    psum += p;
                    pv[r] = f2h(p);
                }
                int ch = (2 * rb + (g >> 1)) ^ sw;
                *(u16x4*)&Ps[w][qc * 16 + qi][8 * ch + 4 * (g & 1)] = pv;
            }
            psum += __shfl_xor(psum, 16);
            psum += __shfl_xor(psum, 32);
            l_run[qc] += psum;
        }

        // ---- PV: O^T += V^T P^T ; V frags shared across q-blocks
        #pragma unroll
        for (int kc = 0; kc < 2; ++kc) {
            half8 pf0 = *(const half8*)&Ps[w][qi][8 * ((4 * kc + g) ^ sw)];
            half8 pf1 = *(const half8*)&Ps[w][16 + qi][8 * ((4 * kc + g) ^ sw)];
            #pragma unroll
            for (int rb = 0; rb < 4; ++rb) {
                half8 va = *(const half8*)&VtT[cur][rb * 16 + qi][8 * ((4 * kc + g) ^ sw)];
                oacc[0][rb] = __builtin_amdgcn_mfma_f32_16x16x32_f16(va, pf0, oacc[0][rb], 0, 0, 0);
                oacc[1][rb] = __builtin_amdgcn_mfma_f32_16x16x32_f16(va, pf1, oacc[1][rb], 0, 0, 0);
            }
        }

        // ---- write next V^T, then the single barrier
        if (has_next) {
            #pragma unroll
            for (int i = 0; i < 4; ++i) {
                int d = dg * 4 + i;
                u16x4 wvec = { vpre[0][i], vpre[1][i], vpre[2][i], vpre[3][i] };
                *(u16x4*)&VtT[cur ^ 1][d][8 * ((kvg >> 1) ^ (d & 7)) + 4 * (kvg & 1)] = wvec;
            }
        }
        __syncthreads();
    }

    // ---- epilogue: normalized O (fp16) + (m,l) per q-row, per split
    #pragma unroll
    for (int qc = 0; qc < 2; ++qc) {
        const int qrow = q0 + w * 32 + qc * 16 + qi;
        const float inv = 1.f / l_run[qc];
        const size_t orow = (size_t)z * NROWS * HD_ +
                            ((size_t)bh * S_ + qrow) * HD_;
        #pragma unroll
        for (int rb = 0; rb < 4; ++rb) {
            u16x4 ov;
            #pragma unroll
            for (int r = 0; r < 4; ++r) ov[r] = f2h(oacc[qc][rb][r] * inv);
            *(u16x4*)&On[orow + rb * 16 + g * 4] = ov;
        }
        if (g == 0) {
            float2 v; v.x = m_run[qc]; v.y = l_run[qc];
            ml[(size_t)z * NROWS + (size_t)bh * S_ + qrow] = v;
        }
    }
}

// ---------------------------------------------------------------------------
// Combine the 2 kv-splits: out = sum_i w_i * O_i / sum_i w_i,
// w_i = l_i * 2^(m_i - M). Writes aoh in [B,S,E] fp16 for the out-projection.
// ---------------------------------------------------------------------------
__global__ __launch_bounds__(256)
void attn_combine(const ushort_t* __restrict__ On, const float2* __restrict__ ml,
                  ushort_t* __restrict__ aoh)
{
    const int gid = blockIdx.x * 256 + threadIdx.x;   // 262144 total
    const int row = gid >> 2, dp = gid & 3;           // 4 threads/row, 16 d each
    float2 a = ml[row];
    float2 b2 = ml[NROWS + row];
    const float Mx = fmaxf(a.x, b2.x);
    const float w1 = a.y * exp2f(a.x - Mx);
    const float w2 = b2.y * exp2f(b2.x - Mx);
    const float inv = 1.f / (w1 + w2);
    const float c1 = w1 * inv, c2 = w2 * inv;

    const size_t o1 = (size_t)row * HD_ + dp * 16;
    const size_t o2 = (size_t)NROWS * HD_ + o1;
    const int bh = row >> 11, s = row & (S_ - 1);
    const int b = bh >> 4, h = bh & 15;
    ushort_t* dst = &aoh[((size_t)(b * S_ + s)) * E_ + h * HD_ + dp * 16];
    #pragma unroll
    for (int c = 0; c < 2; ++c) {
        u16x8 v1 = *(const u16x8*)&On[o1 + c * 8];
        u16x8 v2 = *(const u16x8*)&On[o2 + c * 8];
        u16x8 o;
        #pragma unroll
        for (int e = 0; e < 8; ++e)
            o[e] = f2h(c1 * h2f(v1[e]) + c2 * h2f(v2[e]));
        *(u16x8*)&dst[c * 8] = o;
    }
}

extern "C" void kernel_launch(void* const* d_in, const int* in_sizes, int n_in,
                              void* d_out, int out_size, void* d_ws, size_t ws_size,
                              hipStream_t stream) {
    const float* x  = (const float*)d_in[0];
    const float* Wq = (const float*)d_in[1];
    const float* bq = (const float*)d_in[2];
    const float* Wk = (const float*)d_in[3];
    const float* bk = (const float*)d_in[4];
    const float* Wv = (const float*)d_in[5];
    const float* bv = (const float*)d_in[6];
    const float* Wo = (const float*)d_in[7];
    const float* bo = (const float*)d_in[8];
    float* out = (float*)d_out;

    const size_t T4 = (size_t)B_ * S_ * E_;   // 4,194,304
    const size_t W1 = (size_t)E_ * E_;        // 1,048,576
    ushort_t* xh  = (ushort_t*)d_ws;          // fp16 x  [B,S,E]
    ushort_t* Wqh = xh  + T4;
    ushort_t* Wkh = Wqh + W1;
    ushort_t* Wvh = Wkh + W1;
    ushort_t* Woh = Wvh + W1;
    ushort_t* qh  = Woh + W1;                 // fp16 [B,H,S,HD]
    ushort_t* kh  = qh  + T4;
    ushort_t* vh  = kh  + T4;
    ushort_t* On  = vh  + T4;                 // fp16 partials [2][BH,S,HD]
    float2*   ml  = (float2*)(On + 2 * T4);   // [2][NROWS]
    float*    bcat = (float*)(ml + 2 * NROWS);
    ushort_t* aoh = xh;                       // alias: xh dead after QKV GEMM

    dim3 blk(256);
    conv_pack<<<2048, blk, 0, stream>>>(x, Wq, Wk, Wv, Wo, bq, bk, bv,
                                        xh, Wqh, Wkh, Wvh, Woh, bcat);

    gemm_qkv<<<24 * 32, blk, 0, stream>>>(xh, Wqh, Wkh, Wvh, bcat, qh, kh, vh);

    dim3 ga(S_ / 128, BH_, 2);                // (16, 32, 2) = 1024 blocks
    attn_mfma<<<ga, blk, 0, stream>>>(qh, kh, vh, On, ml);

    attn_combine<<<(NROWS * 4) / 256, blk, 0, stream>>>(On, ml, aoh);

    gemm_out<<<16 * 32, blk, 0, stream>>>(aoh, Woh, bo, out);
}

// Round 9
// 232.922 us; speedup vs baseline: 9.8038x; 1.0222x over previous
//
#include <hip/hip_runtime.h>

#define B_ 2
#define S_ 2048
#define E_ 1024
#define H_ 16
#define HD_ 64
#define M_ (B_ * S_)      // 4096
#define BH_ (B_ * H_)     // 32
#define NROWS (BH_ * S_)  // 65536

typedef __attribute__((ext_vector_type(8))) _Float16 half8;
typedef __attribute__((ext_vector_type(2))) __fp16 fp16x2;
typedef __attribute__((ext_vector_type(4))) float f32x4;
typedef __attribute__((ext_vector_type(4))) unsigned short u16x4;
typedef __attribute__((ext_vector_type(8))) unsigned short u16x8;
typedef unsigned short ushort_t;

static __device__ __forceinline__ ushort_t f2h(float f) {
    union { _Float16 h; ushort_t u; } c; c.h = (_Float16)f; return c.u;
}
static __device__ __forceinline__ float h2f(ushort_t u) {
    union { _Float16 h; ushort_t u; } c; c.u = u; return (float)c.h;
}
static __device__ __forceinline__ unsigned int pk2h(float a, float b) {
    union { fp16x2 h; unsigned int u; } c;
    c.h = __builtin_amdgcn_cvt_pkrtz(a, b);
    return c.u;
}
// async global->LDS, 16B/lane; LDS dest = wave-uniform base + lane*16
static __device__ __forceinline__ void gl2lds16(const ushort_t* g, ushort_t* l) {
    __builtin_amdgcn_global_load_lds(
        (const __attribute__((address_space(1))) unsigned int*)g,
        (__attribute__((address_space(3))) unsigned int*)l,
        16, 0, 0);
}

// ---------------------------------------------------------------------------
// Conversion: x, Wq, Wk, Wv, Wo -> fp16; QKV bias concat (fp32).
// ---------------------------------------------------------------------------
__global__ __launch_bounds__(256)
void conv_pack(const float* __restrict__ x,  const float* __restrict__ Wq,
               const float* __restrict__ Wk, const float* __restrict__ Wv,
               const float* __restrict__ Wo, const float* __restrict__ bq,
               const float* __restrict__ bk, const float* __restrict__ bv,
               ushort_t* __restrict__ xh,  ushort_t* __restrict__ Wqh,
               ushort_t* __restrict__ Wkh, ushort_t* __restrict__ Wvh,
               ushort_t* __restrict__ Woh, float* __restrict__ bcat)
{
    const int NX = (B_ * S_ * E_) / 4;   // 1,048,576 float4 units
    const int NW = (E_ * E_) / 4;        // 262,144
    const int total = NX + 4 * NW + 768;
    for (int u = blockIdx.x * blockDim.x + threadIdx.x; u < total;
         u += gridDim.x * blockDim.x) {
        if (u < NX) {
            float4 v = ((const float4*)x)[u];
            u16x4 o = { f2h(v.x), f2h(v.y), f2h(v.z), f2h(v.w) };
            ((u16x4*)xh)[u] = o;
        } else if (u < NX + 4 * NW) {
            int r = (u - NX) >> 18;          // NW = 2^18
            int i = (u - NX) & (NW - 1);
            const float* src = (r == 0) ? Wq : (r == 1) ? Wk : (r == 2) ? Wv : Wo;
            ushort_t*    dst = (r == 0) ? Wqh : (r == 1) ? Wkh : (r == 2) ? Wvh : Woh;
            float4 v = ((const float4*)src)[i];
            u16x4 o = { f2h(v.x), f2h(v.y), f2h(v.z), f2h(v.w) };
            ((u16x4*)dst)[i] = o;
        } else {
            int i = u - NX - 4 * NW;         // 0..767
            int r = i >> 8, ii = i & 255;
            const float* src = (r == 0) ? bq : (r == 1) ? bk : bv;
            ((float4*)bcat)[r * 256 + ii] = ((const float4*)src)[ii];
        }
    }
}

// ---------------------------------------------------------------------------
// Fused QKV GEMM, fp16 MFMA, m97 structure (128x128, BK=64, single buffer,
// 2 barriers/K-step, glds(16B) pre-swizzled source). Operand-swapped MFMA
// (accT[j][i] = W x A^T) so each lane's 4 acc elems are consecutive n ->
// u16x4 epilogue stores. q region scaled by 0.125*log2(e).
// ---------------------------------------------------------------------------
__global__ __launch_bounds__(256)
void gemm_qkv(const ushort_t* __restrict__ Ah, const ushort_t* __restrict__ W0p,
              const ushort_t* __restrict__ W1p, const ushort_t* __restrict__ W2p,
              const float* __restrict__ bias,
              ushort_t* __restrict__ O0, ushort_t* __restrict__ O1,
              ushort_t* __restrict__ O2)
{
    __shared__ ushort_t As[128 * 64];
    __shared__ ushort_t Ws[128 * 64];

    const int nwg = 24 * 32;   // 768, %8==0 -> bijective XCD swizzle
    const int b0  = blockIdx.x;
    const int bid = (b0 & 7) * (nwg >> 3) + (b0 >> 3);
    const int bx = bid % 24, by = bid / 24;
    const int m0 = by * 128, n0 = bx * 128;

    const int t = threadIdx.x;
    const int w = t >> 6, lane = t & 63;
    const int g = lane >> 4, qi = lane & 15, sw = qi & 7;
    const int wr = w >> 1, wc = w & 1;

    const int region = n0 >> 10;           // tile never straddles regions
    const ushort_t* WA = (region == 0) ? W0p : (region == 1) ? W1p : W2p;
    const int nw0 = n0 & 1023;

    f32x4 accT[4][4];                       // [j = n-block][i = m-block]
    #pragma unroll
    for (int j = 0; j < 4; ++j)
        #pragma unroll
        for (int i = 0; i < 4; ++i) accT[j][i] = (f32x4){0.f, 0.f, 0.f, 0.f};

    for (int kt = 0; kt < 16; ++kt) {
        __syncthreads();
        const int k0 = kt * 64;
        #pragma unroll
        for (int it = 0; it < 4; ++it) {
            int idx = (it * 4 + w) * 64 + lane;
            int row = idx >> 3, c8 = idx & 7;
            gl2lds16(&Ah[(size_t)(m0 + row) * E_ + k0 + ((c8 ^ (row & 7)) << 3)],
                     &As[(it * 4 + w) * 512]);
        }
        #pragma unroll
        for (int it = 0; it < 4; ++it) {
            int idx = (it * 4 + w) * 64 + lane;
            int row = idx >> 3, c8 = idx & 7;
            gl2lds16(&WA[(size_t)(nw0 + row) * E_ + k0 + ((c8 ^ (row & 7)) << 3)],
                     &Ws[(it * 4 + w) * 512]);
        }
        __syncthreads();

        #pragma unroll
        for (int h = 0; h < 2; ++h) {
            half8 af[4], wf[4];
            #pragma unroll
            for (int i = 0; i < 4; ++i)
                af[i] = *(const half8*)&As[(wr * 64 + i * 16 + qi) * 64 +
                                           (((h * 4 + g) ^ sw) << 3)];
            #pragma unroll
            for (int j = 0; j < 4; ++j)
                wf[j] = *(const half8*)&Ws[(wc * 64 + j * 16 + qi) * 64 +
                                           (((h * 4 + g) ^ sw) << 3)];
            __builtin_amdgcn_s_setprio(1);
            #pragma unroll
            for (int j = 0; j < 4; ++j)
                #pragma unroll
                for (int i = 0; i < 4; ++i)
                    accT[j][i] = __builtin_amdgcn_mfma_f32_16x16x32_f16(
                        wf[j], af[i], accT[j][i], 0, 0, 0);
            __builtin_amdgcn_s_setprio(0);
        }
    }

    ushort_t* Out = (region == 0) ? O0 : (region == 1) ? O1 : O2;
    const float osc = (region == 0) ? 0.18033688f : 1.0f;  // 1/8 * log2(e)
    #pragma unroll
    for (int j = 0; j < 4; ++j) {
        const int nb = n0 + wc * 64 + j * 16 + g * 4;   // 4 consecutive n
        const int nn = nb & 1023;
        const int hh = nn >> 6, d0 = nn & 63;
        const float4 b4 = *(const float4*)&bias[nb];
        #pragma unroll
        for (int i = 0; i < 4; ++i) {
            const int m = m0 + wr * 64 + i * 16 + qi;
            const int b = m >> 11, s = m & (S_ - 1);
            u16x4 ov;
            ov[0] = f2h((accT[j][i][0] + b4.x) * osc);
            ov[1] = f2h((accT[j][i][1] + b4.y) * osc);
            ov[2] = f2h((accT[j][i][2] + b4.z) * osc);
            ov[3] = f2h((accT[j][i][3] + b4.w) * osc);
            *(u16x4*)&Out[(((size_t)(b * H_ + hh)) * S_ + s) * HD_ + d0] = ov;
        }
    }
}

// ---------------------------------------------------------------------------
// Output projection GEMM, fp16 single-pass. 128x64 tile, double-buffered.
// Operand-swapped MFMA -> float4 epilogue stores.
// ---------------------------------------------------------------------------
__global__ __launch_bounds__(256)
void gemm_out(const ushort_t* __restrict__ Ah, const ushort_t* __restrict__ Wh,
              const float* __restrict__ bo, float* __restrict__ Of)
{
    __shared__ ushort_t As[2][128 * 64];
    __shared__ ushort_t Ws[2][64 * 64];

    const int nwg = 16 * 32;   // 512
    const int b0  = blockIdx.x;
    const int bid = (b0 & 7) * (nwg >> 3) + (b0 >> 3);
    const int bx = bid % 16, by = bid / 16;
    const int m0 = by * 128, n0 = bx * 64;

    const int t = threadIdx.x;
    const int w = t >> 6, lane = t & 63;
    const int g = lane >> 4, qi = lane & 15, sw = qi & 7;
    const int wr = w >> 1, wc = w & 1;

    auto stage = [&](int buf, int kt) {
        const int k0 = kt * 64;
        #pragma unroll
        for (int it = 0; it < 4; ++it) {
            int idx = (it * 4 + w) * 64 + lane;
            int row = idx >> 3, c8 = idx & 7;
            gl2lds16(&Ah[(size_t)(m0 + row) * E_ + k0 + ((c8 ^ (row & 7)) << 3)],
                     &As[buf][(it * 4 + w) * 512]);
        }
        #pragma unroll
        for (int it = 0; it < 2; ++it) {
            int idx = (it * 4 + w) * 64 + lane;
            int row = idx >> 3, c8 = idx & 7;
            gl2lds16(&Wh[(size_t)(n0 + row) * E_ + k0 + ((c8 ^ (row & 7)) << 3)],
                     &Ws[buf][(it * 4 + w) * 512]);
        }
    };

    f32x4 accT[2][4];
    #pragma unroll
    for (int j = 0; j < 2; ++j)
        #pragma unroll
        for (int i = 0; i < 4; ++i) accT[j][i] = (f32x4){0.f, 0.f, 0.f, 0.f};

    stage(0, 0);
    __syncthreads();

    for (int kt = 0; kt < 16; ++kt) {
        const int cur = kt & 1;
        if (kt + 1 < 16) stage(cur ^ 1, kt + 1);
        #pragma unroll
        for (int h = 0; h < 2; ++h) {
            half8 af[4], wf[2];
            #pragma unroll
            for (int i = 0; i < 4; ++i)
                af[i] = *(const half8*)&As[cur][(wr * 64 + i * 16 + qi) * 64 +
                                                (((h * 4 + g) ^ sw) << 3)];
            #pragma unroll
            for (int j = 0; j < 2; ++j)
                wf[j] = *(const half8*)&Ws[cur][(wc * 32 + j * 16 + qi) * 64 +
                                                (((h * 4 + g) ^ sw) << 3)];
            __builtin_amdgcn_s_setprio(1);
            #pragma unroll
            for (int j = 0; j < 2; ++j)
                #pragma unroll
                for (int i = 0; i < 4; ++i)
                    accT[j][i] = __builtin_amdgcn_mfma_f32_16x16x32_f16(
                        wf[j], af[i], accT[j][i], 0, 0, 0);
            __builtin_amdgcn_s_setprio(0);
        }
        __syncthreads();
    }

    #pragma unroll
    for (int j = 0; j < 2; ++j) {
        const int nb = n0 + wc * 32 + j * 16 + g * 4;
        const float4 b4 = *(const float4*)&bo[nb];
        #pragma unroll
        for (int i = 0; i < 4; ++i) {
            const int m = m0 + wr * 64 + i * 16 + qi;
            float4 ov;
            ov.x = accT[j][i][0] + b4.x;
            ov.y = accT[j][i][1] + b4.y;
            ov.z = accT[j][i][2] + b4.z;
            ov.w = accT[j][i][3] + b4.w;
            *(float4*)&Of[(size_t)m * E_ + nb] = ov;
        }
    }
}

// ---------------------------------------------------------------------------
// MFMA flash attention v4, fp16, KV-SPLIT x2.
// vs v3: (1) l tracked via ones-column MFMA (psum adds/shuffles deleted;
// rescale rides the deferred-max path); (2) packed cvt_pkrtz for P->fp16;
// (3) V^T write swizzle gains ^(d>>3) -> 4-way (was 8-way) bank conflicts;
// read side matched with ^(2rb + (qi>>3)).
// ---------------------------------------------------------------------------
__global__ __launch_bounds__(256)
void attn_mfma(const ushort_t* __restrict__ Qg, const ushort_t* __restrict__ Kg,
               const ushort_t* __restrict__ Vg,
               ushort_t* __restrict__ On, float2* __restrict__ ml)
{
    __shared__ ushort_t Ks[2][64][64];    // K tile [kv][d], XOR-chunk swizzled
    __shared__ ushort_t VtT[2][64][64];   // V^T tile [d][kv], swizzled (+d>>3)
    __shared__ ushort_t Ps[4][32][64];    // per-wave P [q][kv], swizzled

    const int t    = threadIdx.x;
    const int w    = t >> 6;
    const int lane = t & 63;
    const int g    = lane >> 4;
    const int qi   = lane & 15;
    const int sw   = qi & 7;
    const int bh   = blockIdx.y;
    const int q0   = blockIdx.x * 128;
    const int z    = blockIdx.z;          // kv half
    const int t0   = z * 16, t1 = t0 + 16;
    const size_t base = (size_t)bh * S_ * HD_;
    const int kvg = t >> 4, dg = t & 15;  // V staging roles

    auto stageK = [&](int buf, int tile) {
        const size_t nb = base + (size_t)tile * 64 * HD_;
        #pragma unroll
        for (int it = 0; it < 2; ++it) {
            int u = w * 128 + it * 64 + lane;
            int row = u >> 3, c8 = u & 7;
            gl2lds16(&Kg[nb + (size_t)row * HD_ + ((c8 ^ (row & 7)) << 3)],
                     &Ks[buf][0][0] + (size_t)(w * 128 + it * 64) * 8);
        }
    };
    auto writeV = [&](int buf, const u16x4* vv) {
        #pragma unroll
        for (int i = 0; i < 4; ++i) {
            int d = dg * 4 + i;
            u16x4 wvec = { vv[0][i], vv[1][i], vv[2][i], vv[3][i] };
            int p = ((kvg >> 1) ^ (d & 7) ^ (d >> 3)) & 7;
            *(u16x4*)&VtT[buf][d][8 * p + 4 * (kvg & 1)] = wvec;
        }
    };

    // Q fragments straight from global (once per block)
    half8 qf[2][2];
    #pragma unroll
    for (int qc = 0; qc < 2; ++qc)
        #pragma unroll
        for (int h = 0; h < 2; ++h)
            qf[qc][h] = *(const half8*)&Qg[base +
                (size_t)(q0 + w * 32 + qc * 16 + qi) * HD_ + (h * 4 + g) * 8];

    // prologue: stage first tile of this split
    stageK(0, t0);
    {
        const size_t nb = base + (size_t)t0 * 64 * HD_;
        u16x4 vv[4];
        #pragma unroll
        for (int j = 0; j < 4; ++j)
            vv[j] = *(const u16x4*)&Vg[nb + (size_t)(kvg * 4 + j) * HD_ + dg * 4];
        writeV(0, vv);
    }
    __syncthreads();

    const half8 ones = { (_Float16)1, (_Float16)1, (_Float16)1, (_Float16)1,
                         (_Float16)1, (_Float16)1, (_Float16)1, (_Float16)1 };

    float m_run[2] = { -3.0e38f, -3.0e38f };
    f32x4 lacc[2];
    f32x4 oacc[2][4];
    #pragma unroll
    for (int qc = 0; qc < 2; ++qc) {
        lacc[qc] = (f32x4){0.f, 0.f, 0.f, 0.f};
        #pragma unroll
        for (int rb = 0; rb < 4; ++rb) oacc[qc][rb] = (f32x4){0.f, 0.f, 0.f, 0.f};
    }

    for (int tile = t0; tile < t1; ++tile) {
        const int cur = tile & 1;
        const bool has_next = (tile + 1 < t1);

        u16x4 vpre[4];
        if (has_next) {
            stageK(cur ^ 1, tile + 1);
            const size_t nb = base + (size_t)(tile + 1) * 64 * HD_;
            #pragma unroll
            for (int j = 0; j < 4; ++j)
                vpre[j] = *(const u16x4*)&Vg[nb + (size_t)(kvg * 4 + j) * HD_ + dg * 4];
        }

        // ---- QK^T -> S^T for both q-blocks; K frags shared
        f32x4 sacc[2][4];
        #pragma unroll
        for (int rb = 0; rb < 4; ++rb) {
            half8 ka0 = *(const half8*)&Ks[cur][rb * 16 + qi][8 * ((0 + g) ^ sw)];
            half8 ka1 = *(const half8*)&Ks[cur][rb * 16 + qi][8 * ((4 + g) ^ sw)];
            #pragma unroll
            for (int qc = 0; qc < 2; ++qc) {
                f32x4 zz = (f32x4){0.f, 0.f, 0.f, 0.f};
                zz = __builtin_amdgcn_mfma_f32_16x16x32_f16(ka0, qf[qc][0], zz, 0, 0, 0);
                zz = __builtin_amdgcn_mfma_f32_16x16x32_f16(ka1, qf[qc][1], zz, 0, 0, 0);
                sacc[qc][rb] = zz;
            }
        }

        // ---- online softmax (exp2 domain, defer-max); l handled by MFMA
        #pragma unroll
        for (int qc = 0; qc < 2; ++qc) {
            float smax = sacc[qc][0][0];
            #pragma unroll
            for (int rb = 0; rb < 4; ++rb)
                #pragma unroll
                for (int r = 0; r < 4; ++r) smax = fmaxf(smax, sacc[qc][rb][r]);
            smax = fmaxf(smax, __shfl_xor(smax, 16));
            smax = fmaxf(smax, __shfl_xor(smax, 32));
            if (__any(smax > m_run[qc] + 8.0f)) {
                const float mnew  = fmaxf(m_run[qc], smax);
                const float alpha = exp2f(m_run[qc] - mnew);
                #pragma unroll
                for (int r = 0; r < 4; ++r) lacc[qc][r] *= alpha;
                #pragma unroll
                for (int rb = 0; rb < 4; ++rb)
                    #pragma unroll
                    for (int r = 0; r < 4; ++r) oacc[qc][rb][r] *= alpha;
                m_run[qc] = mnew;
            }
            const float mq = m_run[qc];
            #pragma unroll
            for (int rb = 0; rb < 4; ++rb) {
                uint2 pw;
                pw.x = pk2h(exp2f(sacc[qc][rb][0] - mq), exp2f(sacc[qc][rb][1] - mq));
                pw.y = pk2h(exp2f(sacc[qc][rb][2] - mq), exp2f(sacc[qc][rb][3] - mq));
                int ch = (2 * rb + (g >> 1)) ^ sw;
                *(uint2*)&Ps[w][qc * 16 + qi][8 * ch + 4 * (g & 1)] = pw;
            }
        }

        // ---- PV: O^T += V^T P^T  (ones row accumulates l)
        #pragma unroll
        for (int kc = 0; kc < 2; ++kc) {
            half8 pf0 = *(const half8*)&Ps[w][qi][8 * ((4 * kc + g) ^ sw)];
            half8 pf1 = *(const half8*)&Ps[w][16 + qi][8 * ((4 * kc + g) ^ sw)];
            lacc[0] = __builtin_amdgcn_mfma_f32_16x16x32_f16(ones, pf0, lacc[0], 0, 0, 0);
            lacc[1] = __builtin_amdgcn_mfma_f32_16x16x32_f16(ones, pf1, lacc[1], 0, 0, 0);
            #pragma unroll
            for (int rb = 0; rb < 4; ++rb) {
                int p = ((4 * kc + g) ^ sw ^ (2 * rb + (qi >> 3))) & 7;
                half8 va = *(const half8*)&VtT[cur][rb * 16 + qi][8 * p];
                oacc[0][rb] = __builtin_amdgcn_mfma_f32_16x16x32_f16(va, pf0, oacc[0][rb], 0, 0, 0);
                oacc[1][rb] = __builtin_amdgcn_mfma_f32_16x16x32_f16(va, pf1, oacc[1][rb], 0, 0, 0);
            }
        }

        // ---- write next V^T, then the single barrier
        if (has_next) writeV(cur ^ 1, vpre);
        __syncthreads();
    }

    // ---- epilogue: normalized O (fp16) + (m,l) per q-row, per split
    #pragma unroll
    for (int qc = 0; qc < 2; ++qc) {
        const int qrow = q0 + w * 32 + qc * 16 + qi;
        const float lsum = lacc[qc][0];
        const float inv = 1.f / lsum;
        const size_t orow = (size_t)z * NROWS * HD_ +
                            ((size_t)bh * S_ + qrow) * HD_;
        #pragma unroll
        for (int rb = 0; rb < 4; ++rb) {
            u16x4 ov;
            #pragma unroll
            for (int r = 0; r < 4; ++r) ov[r] = f2h(oacc[qc][rb][r] * inv);
            *(u16x4*)&On[orow + rb * 16 + g * 4] = ov;
        }
        if (g == 0) {
            float2 v; v.x = m_run[qc]; v.y = lsum;
            ml[(size_t)z * NROWS + (size_t)bh * S_ + qrow] = v;
        }
    }
}

// ---------------------------------------------------------------------------
// Combine the 2 kv-splits: out = sum_i w_i * O_i / sum_i w_i,
// w_i = l_i * 2^(m_i - M). Writes aoh in [B,S,E] fp16.
// ---------------------------------------------------------------------------
__global__ __launch_bounds__(256)
void attn_combine(const ushort_t* __restrict__ On, const float2* __restrict__ ml,
                  ushort_t* __restrict__ aoh)
{
    const int gid = blockIdx.x * 256 + threadIdx.x;   // 262144 total
    const int row = gid >> 2, dp = gid & 3;
    float2 a = ml[row];
    float2 b2 = ml[NROWS + row];
    const float Mx = fmaxf(a.x, b2.x);
    const float w1 = a.y * exp2f(a.x - Mx);
    const float w2 = b2.y * exp2f(b2.x - Mx);
    const float inv = 1.f / (w1 + w2);
    const float c1 = w1 * inv, c2 = w2 * inv;

    const size_t o1 = (size_t)row * HD_ + dp * 16;
    const size_t o2 = (size_t)NROWS * HD_ + o1;
    const int bh = row >> 11, s = row & (S_ - 1);
    const int b = bh >> 4, h = bh & 15;
    ushort_t* dst = &aoh[((size_t)(b * S_ + s)) * E_ + h * HD_ + dp * 16];
    #pragma unroll
    for (int c = 0; c < 2; ++c) {
        u16x8 v1 = *(const u16x8*)&On[o1 + c * 8];
        u16x8 v2 = *(const u16x8*)&On[o2 + c * 8];
        u16x8 o;
        #pragma unroll
        for (int e = 0; e < 8; ++e)
            o[e] = f2h(c1 * h2f(v1[e]) + c2 * h2f(v2[e]));
        *(u16x8*)&dst[c * 8] = o;
    }
}

extern "C" void kernel_launch(void* const* d_in, const int* in_sizes, int n_in,
                              void* d_out, int out_size, void* d_ws, size_t ws_size,
                              hipStream_t stream) {
    const float* x  = (const float*)d_in[0];
    const float* Wq = (const float*)d_in[1];
    const float* bq = (const float*)d_in[2];
    const float* Wk = (const float*)d_in[3];
    const float* bk = (const float*)d_in[4];
    const float* Wv = (const float*)d_in[5];
    const float* bv = (const float*)d_in[6];
    const float* Wo = (const float*)d_in[7];
    const float* bo = (const float*)d_in[8];
    float* out = (float*)d_out;

    const size_t T4 = (size_t)B_ * S_ * E_;   // 4,194,304
    const size_t W1 = (size_t)E_ * E_;        // 1,048,576
    ushort_t* xh  = (ushort_t*)d_ws;          // fp16 x  [B,S,E]
    ushort_t* Wqh = xh  + T4;
    ushort_t* Wkh = Wqh + W1;
    ushort_t* Wvh = Wkh + W1;
    ushort_t* Woh = Wvh + W1;
    ushort_t* qh  = Woh + W1;                 // fp16 [B,H,S,HD]
    ushort_t* kh  = qh  + T4;
    ushort_t* vh  = kh  + T4;
    ushort_t* On  = vh  + T4;                 // fp16 partials [2][BH,S,HD]
    float2*   ml  = (float2*)(On + 2 * T4);   // [2][NROWS]
    float*    bcat = (float*)(ml + 2 * NROWS);
    ushort_t* aoh = xh;                       // alias: xh dead after QKV GEMM

    dim3 blk(256);
    conv_pack<<<2048, blk, 0, stream>>>(x, Wq, Wk, Wv, Wo, bq, bk, bv,
                                        xh, Wqh, Wkh, Wvh, Woh, bcat);

    gemm_qkv<<<24 * 32, blk, 0, stream>>>(xh, Wqh, Wkh, Wvh, bcat, qh, kh, vh);

    dim3 ga(S_ / 128, BH_, 2);                // (16, 32, 2) = 1024 blocks
    attn_mfma<<<ga, blk, 0, stream>>>(qh, kh, vh, On, ml);

    attn_combine<<<(NROWS * 4) / 256, blk, 0, stream>>>(On, ml, aoh);

    gemm_out<<<16 * 32, blk, 0, stream>>>(aoh, Woh, bo, out);
}

// Round 12
// 223.877 us; speedup vs baseline: 10.1999x; 1.0404x over previous
//
#include <hip/hip_runtime.h>

#define B_ 2
#define S_ 2048
#define E_ 1024
#define H_ 16
#define HD_ 64
#define M_ (B_ * S_)      // 4096
#define BH_ (B_ * H_)     // 32
#define NROWS (BH_ * S_)  // 65536

typedef __attribute__((ext_vector_type(8))) _Float16 half8;
typedef __attribute__((ext_vector_type(2))) __fp16 fp16x2;
typedef __attribute__((ext_vector_type(4))) float f32x4;
typedef __attribute__((ext_vector_type(4))) unsigned short u16x4;
typedef __attribute__((ext_vector_type(8))) unsigned short u16x8;
typedef unsigned short ushort_t;

static __device__ __forceinline__ ushort_t f2h(float f) {
    union { _Float16 h; ushort_t u; } c; c.h = (_Float16)f; return c.u;
}
static __device__ __forceinline__ float h2f(ushort_t u) {
    union { _Float16 h; ushort_t u; } c; c.u = u; return (float)c.h;
}
static __device__ __forceinline__ unsigned int pk2h(float a, float b) {
    union { fp16x2 h; unsigned int u; } c;
    c.h = __builtin_amdgcn_cvt_pkrtz(a, b);
    return c.u;
}
// async global->LDS, 16B/lane; LDS dest = wave-uniform base + lane*16
static __device__ __forceinline__ void gl2lds16(const ushort_t* g, ushort_t* l) {
    __builtin_amdgcn_global_load_lds(
        (const __attribute__((address_space(1))) unsigned int*)g,
        (__attribute__((address_space(3))) unsigned int*)l,
        16, 0, 0);
}

// ---------------------------------------------------------------------------
// Conversion: x, Wq, Wk, Wv, Wo -> fp16; QKV bias concat (fp32).
// ---------------------------------------------------------------------------
__global__ __launch_bounds__(256)
void conv_pack(const float* __restrict__ x,  const float* __restrict__ Wq,
               const float* __restrict__ Wk, const float* __restrict__ Wv,
               const float* __restrict__ Wo, const float* __restrict__ bq,
               const float* __restrict__ bk, const float* __restrict__ bv,
               ushort_t* __restrict__ xh,  ushort_t* __restrict__ Wqh,
               ushort_t* __restrict__ Wkh, ushort_t* __restrict__ Wvh,
               ushort_t* __restrict__ Woh, float* __restrict__ bcat)
{
    const int NX = (B_ * S_ * E_) / 4;   // 1,048,576 float4 units
    const int NW = (E_ * E_) / 4;        // 262,144
    const int total = NX + 4 * NW + 768;
    for (int u = blockIdx.x * blockDim.x + threadIdx.x; u < total;
         u += gridDim.x * blockDim.x) {
        if (u < NX) {
            float4 v = ((const float4*)x)[u];
            u16x4 o = { f2h(v.x), f2h(v.y), f2h(v.z), f2h(v.w) };
            ((u16x4*)xh)[u] = o;
        } else if (u < NX + 4 * NW) {
            int r = (u - NX) >> 18;          // NW = 2^18
            int i = (u - NX) & (NW - 1);
            const float* src = (r == 0) ? Wq : (r == 1) ? Wk : (r == 2) ? Wv : Wo;
            ushort_t*    dst = (r == 0) ? Wqh : (r == 1) ? Wkh : (r == 2) ? Wvh : Woh;
            float4 v = ((const float4*)src)[i];
            u16x4 o = { f2h(v.x), f2h(v.y), f2h(v.z), f2h(v.w) };
            ((u16x4*)dst)[i] = o;
        } else {
            int i = u - NX - 4 * NW;         // 0..767
            int r = i >> 8, ii = i & 255;
            const float* src = (r == 0) ? bq : (r == 1) ? bk : bv;
            ((float4*)bcat)[r * 256 + ii] = ((const float4*)src)[ii];
        }
    }
}

// ---------------------------------------------------------------------------
// Fused QKV GEMM (unchanged). fp16 MFMA, 128x128, BK=64, glds(16B),
// operand-swapped epilogue, q scaled by 0.125*log2(e).
// ---------------------------------------------------------------------------
__global__ __launch_bounds__(256)
void gemm_qkv(const ushort_t* __restrict__ Ah, const ushort_t* __restrict__ W0p,
              const ushort_t* __restrict__ W1p, const ushort_t* __restrict__ W2p,
              const float* __restrict__ bias,
              ushort_t* __restrict__ O0, ushort_t* __restrict__ O1,
              ushort_t* __restrict__ O2)
{
    __shared__ ushort_t As[128 * 64];
    __shared__ ushort_t Ws[128 * 64];

    const int nwg = 24 * 32;   // 768, %8==0 -> bijective XCD swizzle
    const int b0  = blockIdx.x;
    const int bid = (b0 & 7) * (nwg >> 3) + (b0 >> 3);
    const int bx = bid % 24, by = bid / 24;
    const int m0 = by * 128, n0 = bx * 128;

    const int t = threadIdx.x;
    const int w = t >> 6, lane = t & 63;
    const int g = lane >> 4, qi = lane & 15, sw = qi & 7;
    const int wr = w >> 1, wc = w & 1;

    const int region = n0 >> 10;           // tile never straddles regions
    const ushort_t* WA = (region == 0) ? W0p : (region == 1) ? W1p : W2p;
    const int nw0 = n0 & 1023;

    f32x4 accT[4][4];                       // [j = n-block][i = m-block]
    #pragma unroll
    for (int j = 0; j < 4; ++j)
        #pragma unroll
        for (int i = 0; i < 4; ++i) accT[j][i] = (f32x4){0.f, 0.f, 0.f, 0.f};

    for (int kt = 0; kt < 16; ++kt) {
        __syncthreads();
        const int k0 = kt * 64;
        #pragma unroll
        for (int it = 0; it < 4; ++it) {
            int idx = (it * 4 + w) * 64 + lane;
            int row = idx >> 3, c8 = idx & 7;
            gl2lds16(&Ah[(size_t)(m0 + row) * E_ + k0 + ((c8 ^ (row & 7)) << 3)],
                     &As[(it * 4 + w) * 512]);
        }
        #pragma unroll
        for (int it = 0; it < 4; ++it) {
            int idx = (it * 4 + w) * 64 + lane;
            int row = idx >> 3, c8 = idx & 7;
            gl2lds16(&WA[(size_t)(nw0 + row) * E_ + k0 + ((c8 ^ (row & 7)) << 3)],
                     &Ws[(it * 4 + w) * 512]);
        }
        __syncthreads();

        #pragma unroll
        for (int h = 0; h < 2; ++h) {
            half8 af[4], wf[4];
            #pragma unroll
            for (int i = 0; i < 4; ++i)
                af[i] = *(const half8*)&As[(wr * 64 + i * 16 + qi) * 64 +
                                           (((h * 4 + g) ^ sw) << 3)];
            #pragma unroll
            for (int j = 0; j < 4; ++j)
                wf[j] = *(const half8*)&Ws[(wc * 64 + j * 16 + qi) * 64 +
                                           (((h * 4 + g) ^ sw) << 3)];
            __builtin_amdgcn_s_setprio(1);
            #pragma unroll
            for (int j = 0; j < 4; ++j)
                #pragma unroll
                for (int i = 0; i < 4; ++i)
                    accT[j][i] = __builtin_amdgcn_mfma_f32_16x16x32_f16(
                        wf[j], af[i], accT[j][i], 0, 0, 0);
            __builtin_amdgcn_s_setprio(0);
        }
    }

    ushort_t* Out = (region == 0) ? O0 : (region == 1) ? O1 : O2;
    const float osc = (region == 0) ? 0.18033688f : 1.0f;  // 1/8 * log2(e)
    #pragma unroll
    for (int j = 0; j < 4; ++j) {
        const int nb = n0 + wc * 64 + j * 16 + g * 4;   // 4 consecutive n
        const int nn = nb & 1023;
        const int hh = nn >> 6, d0 = nn & 63;
        const float4 b4 = *(const float4*)&bias[nb];
        #pragma unroll
        for (int i = 0; i < 4; ++i) {
            const int m = m0 + wr * 64 + i * 16 + qi;
            const int b = m >> 11, s = m & (S_ - 1);
            u16x4 ov;
            ov[0] = f2h((accT[j][i][0] + b4.x) * osc);
            ov[1] = f2h((accT[j][i][1] + b4.y) * osc);
            ov[2] = f2h((accT[j][i][2] + b4.z) * osc);
            ov[3] = f2h((accT[j][i][3] + b4.w) * osc);
            *(u16x4*)&Out[(((size_t)(b * H_ + hh)) * S_ + s) * HD_ + d0] = ov;
        }
    }
}

// ---------------------------------------------------------------------------
// Output projection GEMM (unchanged).
// ---------------------------------------------------------------------------
__global__ __launch_bounds__(256)
void gemm_out(const ushort_t* __restrict__ Ah, const ushort_t* __restrict__ Wh,
              const float* __restrict__ bo, float* __restrict__ Of)
{
    __shared__ ushort_t As[2][128 * 64];
    __shared__ ushort_t Ws[2][64 * 64];

    const int nwg = 16 * 32;   // 512
    const int b0  = blockIdx.x;
    const int bid = (b0 & 7) * (nwg >> 3) + (b0 >> 3);
    const int bx = bid % 16, by = bid / 16;
    const int m0 = by * 128, n0 = bx * 64;

    const int t = threadIdx.x;
    const int w = t >> 6, lane = t & 63;
    const int g = lane >> 4, qi = lane & 15, sw = qi & 7;
    const int wr = w >> 1, wc = w & 1;

    auto stage = [&](int buf, int kt) {
        const int k0 = kt * 64;
        #pragma unroll
        for (int it = 0; it < 4; ++it) {
            int idx = (it * 4 + w) * 64 + lane;
            int row = idx >> 3, c8 = idx & 7;
            gl2lds16(&Ah[(size_t)(m0 + row) * E_ + k0 + ((c8 ^ (row & 7)) << 3)],
                     &As[buf][(it * 4 + w) * 512]);
        }
        #pragma unroll
        for (int it = 0; it < 2; ++it) {
            int idx = (it * 4 + w) * 64 + lane;
            int row = idx >> 3, c8 = idx & 7;
            gl2lds16(&Wh[(size_t)(n0 + row) * E_ + k0 + ((c8 ^ (row & 7)) << 3)],
                     &Ws[buf][(it * 4 + w) * 512]);
        }
    };

    f32x4 accT[2][4];
    #pragma unroll
    for (int j = 0; j < 2; ++j)
        #pragma unroll
        for (int i = 0; i < 4; ++i) accT[j][i] = (f32x4){0.f, 0.f, 0.f, 0.f};

    stage(0, 0);
    __syncthreads();

    for (int kt = 0; kt < 16; ++kt) {
        const int cur = kt & 1;
        if (kt + 1 < 16) stage(cur ^ 1, kt + 1);
        #pragma unroll
        for (int h = 0; h < 2; ++h) {
            half8 af[4], wf[2];
            #pragma unroll
            for (int i = 0; i < 4; ++i)
                af[i] = *(const half8*)&As[cur][(wr * 64 + i * 16 + qi) * 64 +
                                                (((h * 4 + g) ^ sw) << 3)];
            #pragma unroll
            for (int j = 0; j < 2; ++j)
                wf[j] = *(const half8*)&Ws[cur][(wc * 32 + j * 16 + qi) * 64 +
                                                (((h * 4 + g) ^ sw) << 3)];
            __builtin_amdgcn_s_setprio(1);
            #pragma unroll
            for (int j = 0; j < 2; ++j)
                #pragma unroll
                for (int i = 0; i < 4; ++i)
                    accT[j][i] = __builtin_amdgcn_mfma_f32_16x16x32_f16(
                        wf[j], af[i], accT[j][i], 0, 0, 0);
            __builtin_amdgcn_s_setprio(0);
        }
        __syncthreads();
    }

    #pragma unroll
    for (int j = 0; j < 2; ++j) {
        const int nb = n0 + wc * 32 + j * 16 + g * 4;
        const float4 b4 = *(const float4*)&bo[nb];
        #pragma unroll
        for (int i = 0; i < 4; ++i) {
            const int m = m0 + wr * 64 + i * 16 + qi;
            float4 ov;
            ov.x = accT[j][i][0] + b4.x;
            ov.y = accT[j][i][1] + b4.y;
            ov.z = accT[j][i][2] + b4.z;
            ov.w = accT[j][i][3] + b4.w;
            *(float4*)&Of[(size_t)m * E_ + nb] = ov;
        }
    }
}

// ---------------------------------------------------------------------------
// MFMA flash attention v5, fp16, KV-SPLIT x2, 8 WAVES / 256 q-rows per block.
// vs v4: occupancy fix. LDS = K dbuf 16K + V^T dbuf 16K + P 8x4K = 64KB ->
// exactly 2 blocks/CU, grid 512 = 2/CU (no tail) -> 16 waves/CU (was ~6.4).
// Staging role-split: waves 0-3 stage V (reg-transpose, issue-early/
// write-late), waves 4-7 stage K via global_load_lds. Per-wave compute
// stream identical to v4 (32 q-rows, ones-MFMA l, defer-max, cvt_pkrtz).
// ---------------------------------------------------------------------------
__global__ __launch_bounds__(512)
void attn_mfma(const ushort_t* __restrict__ Qg, const ushort_t* __restrict__ Kg,
               const ushort_t* __restrict__ Vg,
               ushort_t* __restrict__ On, float2* __restrict__ ml)
{
    __shared__ ushort_t Ks[2][64][64];    // K tile [kv][d], XOR-chunk swizzled
    __shared__ ushort_t VtT[2][64][64];   // V^T tile [d][kv], swizzled (+d>>3)
    __shared__ ushort_t Ps[8][32][64];    // per-wave P [q][kv], swizzled

    const int t    = threadIdx.x;         // 0..511
    const int w    = t >> 6;              // 0..7
    const int lane = t & 63;
    const int g    = lane >> 4;
    const int qi   = lane & 15;
    const int sw   = qi & 7;
    const int bh   = blockIdx.y;
    const int q0   = blockIdx.x * 256;
    const int z    = blockIdx.z;          // kv half
    const int t0   = z * 16, t1 = t0 + 16;
    const size_t base = (size_t)bh * S_ * HD_;
    const int kvg = (t & 255) >> 4, dg = t & 15;   // V staging roles (waves 0-3)

    // K staging: waves 4-7 cover all 512 16B chunks (2 per lane)
    auto stageK = [&](int buf, int tile) {
        const size_t nb = base + (size_t)tile * 64 * HD_;
        const int wv = w - 4;             // 0..3
        #pragma unroll
        for (int it = 0; it < 2; ++it) {
            int u = wv * 128 + it * 64 + lane;
            int row = u >> 3, c8 = u & 7;
            gl2lds16(&Kg[nb + (size_t)row * HD_ + ((c8 ^ (row & 7)) << 3)],
                     &Ks[buf][0][0] + (size_t)(wv * 128 + it * 64) * 8);
        }
    };
    auto writeV = [&](int buf, const u16x4* vv) {
        #pragma unroll
        for (int i = 0; i < 4; ++i) {
            int d = dg * 4 + i;
            u16x4 wvec = { vv[0][i], vv[1][i], vv[2][i], vv[3][i] };
            int p = ((kvg >> 1) ^ (d & 7) ^ (d >> 3)) & 7;
            *(u16x4*)&VtT[buf][d][8 * p + 4 * (kvg & 1)] = wvec;
        }
    };

    // Q fragments straight from global (once per block)
    half8 qf[2][2];
    #pragma unroll
    for (int qc = 0; qc < 2; ++qc)
        #pragma unroll
        for (int h = 0; h < 2; ++h)
            qf[qc][h] = *(const half8*)&Qg[base +
                (size_t)(q0 + w * 32 + qc * 16 + qi) * HD_ + (h * 4 + g) * 8];

    // prologue: stage first tile of this split
    if (w >= 4) {
        stageK(0, t0);
    } else {
        const size_t nb = base + (size_t)t0 * 64 * HD_;
        u16x4 vv[4];
        #pragma unroll
        for (int j = 0; j < 4; ++j)
            vv[j] = *(const u16x4*)&Vg[nb + (size_t)(kvg * 4 + j) * HD_ + dg * 4];
        writeV(0, vv);
    }
    __syncthreads();

    const half8 ones = { (_Float16)1, (_Float16)1, (_Float16)1, (_Float16)1,
                         (_Float16)1, (_Float16)1, (_Float16)1, (_Float16)1 };

    float m_run[2] = { -3.0e38f, -3.0e38f };
    f32x4 lacc[2];
    f32x4 oacc[2][4];
    #pragma unroll
    for (int qc = 0; qc < 2; ++qc) {
        lacc[qc] = (f32x4){0.f, 0.f, 0.f, 0.f};
        #pragma unroll
        for (int rb = 0; rb < 4; ++rb) oacc[qc][rb] = (f32x4){0.f, 0.f, 0.f, 0.f};
    }

    for (int tile = t0; tile < t1; ++tile) {
        const int cur = tile & 1;
        const bool has_next = (tile + 1 < t1);

        u16x4 vpre[4];
        if (has_next) {
            if (w >= 4) {
                stageK(cur ^ 1, tile + 1);
            } else {
                const size_t nb = base + (size_t)(tile + 1) * 64 * HD_;
                #pragma unroll
                for (int j = 0; j < 4; ++j)
                    vpre[j] = *(const u16x4*)&Vg[nb + (size_t)(kvg * 4 + j) * HD_ + dg * 4];
            }
        }

        // ---- QK^T -> S^T for both q-blocks; K frags shared
        f32x4 sacc[2][4];
        #pragma unroll
        for (int rb = 0; rb < 4; ++rb) {
            half8 ka0 = *(const half8*)&Ks[cur][rb * 16 + qi][8 * ((0 + g) ^ sw)];
            half8 ka1 = *(const half8*)&Ks[cur][rb * 16 + qi][8 * ((4 + g) ^ sw)];
            #pragma unroll
            for (int qc = 0; qc < 2; ++qc) {
                f32x4 zz = (f32x4){0.f, 0.f, 0.f, 0.f};
                zz = __builtin_amdgcn_mfma_f32_16x16x32_f16(ka0, qf[qc][0], zz, 0, 0, 0);
                zz = __builtin_amdgcn_mfma_f32_16x16x32_f16(ka1, qf[qc][1], zz, 0, 0, 0);
                sacc[qc][rb] = zz;
            }
        }

        // ---- online softmax (exp2 domain, defer-max); l handled by MFMA
        #pragma unroll
        for (int qc = 0; qc < 2; ++qc) {
            float smax = sacc[qc][0][0];
            #pragma unroll
            for (int rb = 0; rb < 4; ++rb)
                #pragma unroll
                for (int r = 0; r < 4; ++r) smax = fmaxf(smax, sacc[qc][rb][r]);
            smax = fmaxf(smax, __shfl_xor(smax, 16));
            smax = fmaxf(smax, __shfl_xor(smax, 32));
            if (__any(smax > m_run[qc] + 8.0f)) {
                const float mnew  = fmaxf(m_run[qc], smax);
                const float alpha = exp2f(m_run[qc] - mnew);
                #pragma unroll
                for (int r = 0; r < 4; ++r) lacc[qc][r] *= alpha;
                #pragma unroll
                for (int rb = 0; rb < 4; ++rb)
                    #pragma unroll
                    for (int r = 0; r < 4; ++r) oacc[qc][rb][r] *= alpha;
                m_run[qc] = mnew;
            }
            const float mq = m_run[qc];
            #pragma unroll
            for (int rb = 0; rb < 4; ++rb) {
                uint2 pw;
                pw.x = pk2h(exp2f(sacc[qc][rb][0] - mq), exp2f(sacc[qc][rb][1] - mq));
                pw.y = pk2h(exp2f(sacc[qc][rb][2] - mq), exp2f(sacc[qc][rb][3] - mq));
                int ch = (2 * rb + (g >> 1)) ^ sw;
                *(uint2*)&Ps[w][qc * 16 + qi][8 * ch + 4 * (g & 1)] = pw;
            }
        }

        // ---- PV: O^T += V^T P^T  (ones row accumulates l)
        #pragma unroll
        for (int kc = 0; kc < 2; ++kc) {
            half8 pf0 = *(const half8*)&Ps[w][qi][8 * ((4 * kc + g) ^ sw)];
            half8 pf1 = *(const half8*)&Ps[w][16 + qi][8 * ((4 * kc + g) ^ sw)];
            lacc[0] = __builtin_amdgcn_mfma_f32_16x16x32_f16(ones, pf0, lacc[0], 0, 0, 0);
            lacc[1] = __builtin_amdgcn_mfma_f32_16x16x32_f16(ones, pf1, lacc[1], 0, 0, 0);
            #pragma unroll
            for (int rb = 0; rb < 4; ++rb) {
                int p = ((4 * kc + g) ^ sw ^ (2 * rb + (qi >> 3))) & 7;
                half8 va = *(const half8*)&VtT[cur][rb * 16 + qi][8 * p];
                oacc[0][rb] = __builtin_amdgcn_mfma_f32_16x16x32_f16(va, pf0, oacc[0][rb], 0, 0, 0);
                oacc[1][rb] = __builtin_amdgcn_mfma_f32_16x16x32_f16(va, pf1, oacc[1][rb], 0, 0, 0);
            }
        }

        // ---- write next V^T (waves 0-3), then the single barrier
        if (has_next && w < 4) writeV(cur ^ 1, vpre);
        __syncthreads();
    }

    // ---- epilogue: normalized O (fp16) + (m,l) per q-row, per split
    #pragma unroll
    for (int qc = 0; qc < 2; ++qc) {
        const int qrow = q0 + w * 32 + qc * 16 + qi;
        const float lsum = lacc[qc][0];
        const float inv = 1.f / lsum;
        const size_t orow = (size_t)z * NROWS * HD_ +
                            ((size_t)bh * S_ + qrow) * HD_;
        #pragma unroll
        for (int rb = 0; rb < 4; ++rb) {
            u16x4 ov;
            #pragma unroll
            for (int r = 0; r < 4; ++r) ov[r] = f2h(oacc[qc][rb][r] * inv);
            *(u16x4*)&On[orow + rb * 16 + g * 4] = ov;
        }
        if (g == 0) {
            float2 v; v.x = m_run[qc]; v.y = lsum;
            ml[(size_t)z * NROWS + (size_t)bh * S_ + qrow] = v;
        }
    }
}

// ---------------------------------------------------------------------------
// Combine the 2 kv-splits (unchanged).
// ---------------------------------------------------------------------------
__global__ __launch_bounds__(256)
void attn_combine(const ushort_t* __restrict__ On, const float2* __restrict__ ml,
                  ushort_t* __restrict__ aoh)
{
    const int gid = blockIdx.x * 256 + threadIdx.x;   // 262144 total
    const int row = gid >> 2, dp = gid & 3;
    float2 a = ml[row];
    float2 b2 = ml[NROWS + row];
    const float Mx = fmaxf(a.x, b2.x);
    const float w1 = a.y * exp2f(a.x - Mx);
    const float w2 = b2.y * exp2f(b2.x - Mx);
    const float inv = 1.f / (w1 + w2);
    const float c1 = w1 * inv, c2 = w2 * inv;

    const size_t o1 = (size_t)row * HD_ + dp * 16;
    const size_t o2 = (size_t)NROWS * HD_ + o1;
    const int bh = row >> 11, s = row & (S_ - 1);
    const int b = bh >> 4, h = bh & 15;
    ushort_t* dst = &aoh[((size_t)(b * S_ + s)) * E_ + h * HD_ + dp * 16];
    #pragma unroll
    for (int c = 0; c < 2; ++c) {
        u16x8 v1 = *(const u16x8*)&On[o1 + c * 8];
        u16x8 v2 = *(const u16x8*)&On[o2 + c * 8];
        u16x8 o;
        #pragma unroll
        for (int e = 0; e < 8; ++e)
            o[e] = f2h(c1 * h2f(v1[e]) + c2 * h2f(v2[e]));
        *(u16x8*)&dst[c * 8] = o;
    }
}

extern "C" void kernel_launch(void* const* d_in, const int* in_sizes, int n_in,
                              void* d_out, int out_size, void* d_ws, size_t ws_size,
                              hipStream_t stream) {
    const float* x  = (const float*)d_in[0];
    const float* Wq = (const float*)d_in[1];
    const float* bq = (const float*)d_in[2];
    const float* Wk = (const float*)d_in[3];
    const float* bk = (const float*)d_in[4];
    const float* Wv = (const float*)d_in[5];
    const float* bv = (const float*)d_in[6];
    const float* Wo = (const float*)d_in[7];
    const float* bo = (const float*)d_in[8];
    float* out = (float*)d_out;

    const size_t T4 = (size_t)B_ * S_ * E_;   // 4,194,304
    const size_t W1 = (size_t)E_ * E_;        // 1,048,576
    ushort_t* xh  = (ushort_t*)d_ws;          // fp16 x  [B,S,E]
    ushort_t* Wqh = xh  + T4;
    ushort_t* Wkh = Wqh + W1;
    ushort_t* Wvh = Wkh + W1;
    ushort_t* Woh = Wvh + W1;
    ushort_t* qh  = Woh + W1;                 // fp16 [B,H,S,HD]
    ushort_t* kh  = qh  + T4;
    ushort_t* vh  = kh  + T4;
    ushort_t* On  = vh  + T4;                 // fp16 partials [2][BH,S,HD]
    float2*   ml  = (float2*)(On + 2 * T4);   // [2][NROWS]
    float*    bcat = (float*)(ml + 2 * NROWS);
    ushort_t* aoh = xh;                       // alias: xh dead after QKV GEMM

    dim3 blk(256);
    conv_pack<<<2048, blk, 0, stream>>>(x, Wq, Wk, Wv, Wo, bq, bk, bv,
                                        xh, Wqh, Wkh, Wvh, Woh, bcat);

    gemm_qkv<<<24 * 32, blk, 0, stream>>>(xh, Wqh, Wkh, Wvh, bcat, qh, kh, vh);

    dim3 ga(S_ / 256, BH_, 2);                // (8, 32, 2) = 512 blocks
    attn_mfma<<<ga, dim3(512), 0, stream>>>(qh, kh, vh, On, ml);

    attn_combine<<<(NROWS * 4) / 256, blk, 0, stream>>>(On, ml, aoh);

    gemm_out<<<16 * 32, blk, 0, stream>>>(aoh, Woh, bo, out);
}